// Round 8
// baseline (145.597 us; speedup 1.0000x reference)
//
#include <hip/hip_runtime.h>

// MultiHeadAttn: B=2, T=2048, D=1024, H=16, dh=64
// inputs: Q_seq,K_seq,V_seq [2,2048,1024] f32; Q_len,V_len [2,1] i32; WQ,WK,WV [1024,1024] f32
// output: [2,2048,1024] f32

using short8   = __attribute__((ext_vector_type(8))) short;
using floatx4  = __attribute__((ext_vector_type(4))) float;
using floatx16 = __attribute__((ext_vector_type(16))) float;
using uintx4   = __attribute__((ext_vector_type(4))) unsigned int;
using ushort4v = __attribute__((ext_vector_type(4))) unsigned short;

__device__ __forceinline__ unsigned short f2bf(float f) {
    unsigned int u = __builtin_bit_cast(unsigned int, f);
    u += 0x7fffu + ((u >> 16) & 1u);   // round-to-nearest-even
    return (unsigned short)(u >> 16);
}

// ---------------------------------------------------------------------------
// Kernel 0: fp32 -> bf16 convert of Q_seq/K_seq/V_seq rows that are needed.
// ---------------------------------------------------------------------------
__global__ __launch_bounds__(256) void cvt_kernel(
    const float* __restrict__ Qs, const float* __restrict__ Ks,
    const float* __restrict__ Vs, const int* __restrict__ Qlen,
    const int* __restrict__ Vlen, unsigned short* __restrict__ abf)
{
    int z = blockIdx.y, row = blockIdx.x;
    int b = row >> 11, rib = row & 2047;
    int ql = Qlen[b]; int vl = Vlen[b]; int vle = vl ? vl : 2048;
    int lim = (z == 0) ? ((ql + 127) & ~127) : ((vle + 127) & ~127);
    if (rib >= lim) return;
    const float* src = (z == 0) ? Qs : ((z == 1) ? Ks : Vs);
    int t = threadIdx.x;
    float4 v = *reinterpret_cast<const float4*>(src + (size_t)row * 1024 + t * 4);
    ushort4v o;
    o[0] = f2bf(v.x); o[1] = f2bf(v.y); o[2] = f2bf(v.z); o[3] = f2bf(v.w);
    *reinterpret_cast<ushort4v*>(abf + (size_t)z * 4194304u + (size_t)row * 1024 + t * 4) = o;
}

// ---------------------------------------------------------------------------
// Kernel 1: W [1024][1024] f32  ->  W^T [1024][1024] bf16 (z = 0,1,2)
// ---------------------------------------------------------------------------
__global__ __launch_bounds__(256) void wt_kernel(
    const float* __restrict__ W0, const float* __restrict__ W1,
    const float* __restrict__ W2, unsigned short* __restrict__ out)
{
    __shared__ float tile[64][65];
    int z = blockIdx.z;
    const float* W = (z == 0) ? W0 : ((z == 1) ? W1 : W2);
    unsigned short* O = out + (size_t)z * 1048576u;
    int r0 = blockIdx.y * 64, c0 = blockIdx.x * 64;
    int t = threadIdx.x;
#pragma unroll
    for (int i = 0; i < 16; i++) {
        int idx = t + i * 256; int r = idx >> 6, c = idx & 63;
        tile[r][c] = W[(size_t)(r0 + r) * 1024 + c0 + c];
    }
    __syncthreads();
#pragma unroll
    for (int i = 0; i < 16; i++) {
        int idx = t + i * 256; int c = idx >> 6, r = idx & 63;
        O[(size_t)(c0 + c) * 1024 + r0 + r] = f2bf(tile[r][c]);
    }
}

// ---------------------------------------------------------------------------
// Kernel 2: projection GEMM (unchanged)
// ---------------------------------------------------------------------------
template <bool PRECVT>
__global__ __launch_bounds__(256) void proj_kernel(
    const float* __restrict__ Qs, const float* __restrict__ Ks,
    const float* __restrict__ Vs, const unsigned short* __restrict__ abf,
    const unsigned short* __restrict__ wt,
    const int* __restrict__ Qlen, const int* __restrict__ Vlen,
    unsigned short* __restrict__ q, unsigned short* __restrict__ k,
    unsigned short* __restrict__ vT)
{
    __shared__ alignas(16) unsigned short As[128][72];
    __shared__ alignas(16) unsigned short Bs[128][72];

    int z = blockIdx.z;
    int tid = threadIdx.x;
    int m0 = blockIdx.y * 128, n0 = blockIdx.x * 128;
    int b = m0 >> 11, rib = m0 & 2047;
    int ql = Qlen[b]; int vl = Vlen[b]; int vle = vl ? vl : 2048;
    int lim = (z == 0) ? ((ql + 127) & ~127) : ((vle + 127) & ~127);
    if (rib >= lim) return;

    const float* Af = (z == 0) ? Qs : ((z == 1) ? Ks : Vs);
    const unsigned short* Ab = abf + (size_t)z * 4194304u;
    const unsigned short* Bt = wt + (size_t)z * 1048576u;

    int w = tid >> 6, lane = tid & 63, g = lane >> 4, lr = lane & 15;
    int wr = w >> 1, wc = w & 1;

    floatx4 acc[4][4];
#pragma unroll
    for (int m = 0; m < 4; m++)
#pragma unroll
        for (int n = 0; n < 4; n++) {
#pragma unroll
            for (int r = 0; r < 4; r++) acc[m][n][r] = 0.f;
        }

    int srow = tid >> 1, scol = (tid & 1) * 32;

    short8 pa[4], pb[4];
    float4 fa[8];

    if constexpr (PRECVT) {
#pragma unroll
        for (int i = 0; i < 4; i++)
            pa[i] = *reinterpret_cast<const short8*>(Ab + (size_t)(m0 + srow) * 1024 + scol + i * 8);
    } else {
#pragma unroll
        for (int i = 0; i < 8; i++)
            fa[i] = *reinterpret_cast<const float4*>(Af + (size_t)(m0 + srow) * 1024 + scol + i * 4);
    }
#pragma unroll
    for (int i = 0; i < 4; i++)
        pb[i] = *reinterpret_cast<const short8*>(Bt + (size_t)(n0 + srow) * 1024 + scol + i * 8);

    for (int kb = 0; kb < 1024; kb += 64) {
        __syncthreads();
        if constexpr (PRECVT) {
#pragma unroll
            for (int i = 0; i < 4; i++)
                *reinterpret_cast<short8*>(&As[srow][scol + i * 8]) = pa[i];
        } else {
#pragma unroll
            for (int i = 0; i < 4; i++) {
                short8 h;
                h[0] = (short)f2bf(fa[2*i].x);   h[1] = (short)f2bf(fa[2*i].y);
                h[2] = (short)f2bf(fa[2*i].z);   h[3] = (short)f2bf(fa[2*i].w);
                h[4] = (short)f2bf(fa[2*i+1].x); h[5] = (short)f2bf(fa[2*i+1].y);
                h[6] = (short)f2bf(fa[2*i+1].z); h[7] = (short)f2bf(fa[2*i+1].w);
                *reinterpret_cast<short8*>(&As[srow][scol + i * 8]) = h;
            }
        }
#pragma unroll
        for (int i = 0; i < 4; i++)
            *reinterpret_cast<short8*>(&Bs[srow][scol + i * 8]) = pb[i];
        __syncthreads();

        if (kb + 64 < 1024) {
            if constexpr (PRECVT) {
#pragma unroll
                for (int i = 0; i < 4; i++)
                    pa[i] = *reinterpret_cast<const short8*>(Ab + (size_t)(m0 + srow) * 1024 + kb + 64 + scol + i * 8);
            } else {
#pragma unroll
                for (int i = 0; i < 8; i++)
                    fa[i] = *reinterpret_cast<const float4*>(Af + (size_t)(m0 + srow) * 1024 + kb + 64 + scol + i * 4);
            }
#pragma unroll
            for (int i = 0; i < 4; i++)
                pb[i] = *reinterpret_cast<const short8*>(Bt + (size_t)(n0 + srow) * 1024 + kb + 64 + scol + i * 8);
        }

#pragma unroll
        for (int kc = 0; kc < 2; kc++) {
            short8 af[4], bf[4];
#pragma unroll
            for (int m = 0; m < 4; m++)
                af[m] = *reinterpret_cast<const short8*>(&As[wr * 64 + m * 16 + lr][kc * 32 + g * 8]);
#pragma unroll
            for (int n = 0; n < 4; n++)
                bf[n] = *reinterpret_cast<const short8*>(&Bs[wc * 64 + n * 16 + lr][kc * 32 + g * 8]);
#pragma unroll
            for (int m = 0; m < 4; m++)
#pragma unroll
                for (int n = 0; n < 4; n++)
                    acc[m][n] = __builtin_amdgcn_mfma_f32_16x16x32_bf16(af[m], bf[n], acc[m][n], 0, 0, 0);
        }
    }

    if (z < 2) {
        unsigned short* outp = (z == 0) ? q : k;
#pragma unroll
        for (int m = 0; m < 4; m++) {
            int row0 = m0 + wr * 64 + m * 16 + g * 4;
#pragma unroll
            for (int n = 0; n < 4; n++) {
                int col = n0 + wc * 64 + n * 16 + lr;
#pragma unroll
                for (int r = 0; r < 4; r++)
                    outp[(size_t)(row0 + r) * 1024 + col] = f2bf(acc[m][n][r]);
            }
        }
    } else {
#pragma unroll
        for (int m = 0; m < 4; m++) {
            int row0 = m0 + wr * 64 + m * 16 + g * 4;
            int bb = row0 >> 11, t0 = row0 & 2047;
#pragma unroll
            for (int n = 0; n < 4; n++) {
                int col = n0 + wc * 64 + n * 16 + lr;
                ushort4v pk;
#pragma unroll
                for (int r = 0; r < 4; r++) pk[r] = f2bf(acc[m][n][r]);
                *reinterpret_cast<ushort4v*>(vT + (size_t)(bb * 1024 + col) * 2048 + t0) = pk;
            }
        }
    }
}

// ---------------------------------------------------------------------------
// Kernel 3: flash attention, 32x32 swapped-QK, 8-way KV split.
// 512 thr = 8 waves sharing the SAME 32 q rows; wave w owns KV tiles
// {w, w+8, ...}. Main loop: NO LDS, NO barriers — K/V fragments straight
// from global (L2) into MFMA operand regs, next-tile loads issued right
// after the regs go dead, pinned by sched_barrier(0). 3-stage LDS combine
// tree at the end. Grid 2048 (XCD-balanced: bh&7 = XCD).
// Purpose of split-8: live waves ~8192 (vs 2048 at split-2) -> 4/SIMD
// resident so stalls are TLP-hidden (R3-R7 showed supply-bound occupancy).
// ---------------------------------------------------------------------------
__global__ __launch_bounds__(512, 4) void attn_kernel(
    const unsigned short* __restrict__ q, const unsigned short* __restrict__ k,
    const unsigned short* __restrict__ vT, const int* __restrict__ Qlen,
    const int* __restrict__ Vlen, float* __restrict__ out)
{
    __shared__ float obuf[4][64][33];   // 33792 B: O exchange
    __shared__ float mlm[8][33];        // per-wave m
    __shared__ float mll[8][33];        // per-wave l'

    int tid = threadIdx.x;
    int w = tid >> 6, lane = tid & 63;
    int j = lane & 31, hi = lane >> 5;

    int blk = blockIdx.x;
    int x = blk & 7, idx = blk >> 3;
    int bh = x + 8 * (idx >> 6), qtile = idx & 63;
    int b = bh >> 4, h = bh & 15;
    int qlen = Qlen[b]; int vl = Vlen[b]; int vle = vl ? vl : 2048;
    int qrow0 = qtile * 32;

    if (qrow0 >= qlen) {   // whole block masked -> zeros (block-uniform, pre-barrier)
        int zr = qrow0 + (tid >> 4);
        float* p = out + (size_t)(b * 2048 + zr) * 1024 + h * 64 + (tid & 15) * 4;
        float4 z4; z4.x = 0.f; z4.y = 0.f; z4.z = 0.f; z4.w = 0.f;
        *reinterpret_cast<float4*>(p) = z4;
        return;
    }

    int nt = (vle + 63) >> 6;                      // # 64-key tiles (>= 1)
    int ntw = (nt > w) ? ((nt - w + 7) >> 3) : 0;  // tiles for this wave

    const unsigned short* kbase = k + (size_t)(b * 2048) * 1024 + h * 64 + hi * 8;
    const unsigned short* vbase = vT + (size_t)(b * 1024 + h * 64 + j) * 2048 + hi * 8;
    const unsigned short* vbase2 = vbase + 32 * 2048;

    // ---- initial fragment loads (tile w, clamped)
    short8 kf0[4], kf1[4], vf0[4], vf1[4];
    {
        int t0 = (w < nt) ? w : (nt - 1);
        int kt = t0 << 6;
        const unsigned short* kr0 = kbase + (size_t)(kt + j) * 1024;
        const unsigned short* kr1 = kbase + (size_t)(kt + 32 + j) * 1024;
#pragma unroll
        for (int c = 0; c < 4; c++) {
            kf0[c] = *reinterpret_cast<const short8*>(kr0 + c * 16);
            kf1[c] = *reinterpret_cast<const short8*>(kr1 + c * 16);
            vf0[c] = *reinterpret_cast<const short8*>(vbase + kt + c * 16);
            vf1[c] = *reinterpret_cast<const short8*>(vbase2 + kt + c * 16);
        }
    }
    __builtin_amdgcn_sched_barrier(0);

    // Q fragments: B-operand, lane holds Q[q=qrow0+j][c*16 + hi*8 + 0..7]
    short8 qf[4];
    {
        const unsigned short* qp = q + (size_t)(b * 2048 + qrow0 + j) * 1024 + h * 64 + hi * 8;
#pragma unroll
        for (int c = 0; c < 4; c++) qf[c] = *reinterpret_cast<const short8*>(qp + c * 16);
    }

    floatx16 O0, O1;
#pragma unroll
    for (int t = 0; t < 16; t++) { O0[t] = 0.f; O1[t] = 0.f; }
    float m_r = -3.0e38f, l_r = 0.f;

    const float CEXP = 0.18033688011112042f;   // 0.125 * log2(e)

    for (int m = 0; m < ntw; ++m) {
        int tix = w + 8 * m;
        int kt = tix << 6;
        int tnx = tix + 8; if (tnx >= nt) tnx = nt - 1;   // clamped prefetch target
        int ktn = tnx << 6;

        // ---- QK^T (swapped): col=lane&31=q, row=(t&3)+8*(t>>2)+4*hi
        floatx16 s0, s1;
#pragma unroll
        for (int t = 0; t < 16; t++) { s0[t] = 0.f; s1[t] = 0.f; }
        __builtin_amdgcn_s_setprio(1);
#pragma unroll
        for (int c = 0; c < 4; c++) {
            s0 = __builtin_amdgcn_mfma_f32_32x32x16_bf16(kf0[c], qf[c], s0, 0, 0, 0);
            s1 = __builtin_amdgcn_mfma_f32_32x32x16_bf16(kf1[c], qf[c], s1, 0, 0, 0);
        }
        __builtin_amdgcn_s_setprio(0);

        // ---- K-frags are dead: issue next tile's K loads NOW (fly under softmax+PV)
        {
            const unsigned short* kr0 = kbase + (size_t)(ktn + j) * 1024;
            const unsigned short* kr1 = kbase + (size_t)(ktn + 32 + j) * 1024;
#pragma unroll
            for (int c = 0; c < 4; c++) {
                kf0[c] = *reinterpret_cast<const short8*>(kr0 + c * 16);
                kf1[c] = *reinterpret_cast<const short8*>(kr1 + c * 16);
            }
        }
        __builtin_amdgcn_sched_barrier(0);

        if (kt + 64 > vle) {   // boundary tile: mask keys >= vle
#pragma unroll
            for (int t = 0; t < 16; t++) {
                int kl = (t & 3) + 8 * (t >> 2) + 4 * hi;
                if (kt + kl >= vle)      s0[t] = -8.0e12f;
                if (kt + 32 + kl >= vle) s1[t] = -8.0e12f;
            }
        }

        // ---- online softmax
        float mx = s0[0];
#pragma unroll
        for (int t = 1; t < 16; t++) mx = fmaxf(mx, s0[t]);
#pragma unroll
        for (int t = 0; t < 16; t++) mx = fmaxf(mx, s1[t]);
        float lm = fmaxf(mx, __shfl_xor(mx, 32));

        if (__any(lm > m_r + 64.f)) {
            float mn = fmaxf(m_r, lm);
            float al = __builtin_amdgcn_exp2f((m_r - mn) * CEXP);
            m_r = mn;
            l_r *= al;
#pragma unroll
            for (int t = 0; t < 16; t++) { O0[t] *= al; O1[t] *= al; }
        }
        float nm = -m_r * CEXP;
#pragma unroll
        for (int t = 0; t < 16; t++) {
            s0[t] = __builtin_amdgcn_exp2f(fmaf(s0[t], CEXP, nm));
            s1[t] = __builtin_amdgcn_exp2f(fmaf(s1[t], CEXP, nm));
        }
        float rs = 0.f;
#pragma unroll
        for (int t = 0; t < 16; t++) rs += s0[t] + s1[t];
        l_r += rs;

        // ---- P -> bf16 B-fragments via cvt_pk + permlane32_swap
        unsigned int pbw[4][4];
        {
            unsigned int D[4][2];
#pragma unroll
            for (int s = 0; s < 4; s++) {
                asm("v_cvt_pk_bf16_f32 %0, %1, %2" : "=v"(D[s][0]) : "v"(s0[4*s+0]), "v"(s0[4*s+1]));
                asm("v_cvt_pk_bf16_f32 %0, %1, %2" : "=v"(D[s][1]) : "v"(s0[4*s+2]), "v"(s0[4*s+3]));
            }
#pragma unroll
            for (int u = 0; u < 2; u++) {
                asm volatile("v_permlane32_swap_b32 %0, %1" : "+v"(D[0][u]), "+v"(D[1][u]));
                asm volatile("v_permlane32_swap_b32 %0, %1" : "+v"(D[2][u]), "+v"(D[3][u]));
                pbw[0][u] = D[0][u]; pbw[0][u + 2] = D[1][u];
                pbw[1][u] = D[2][u]; pbw[1][u + 2] = D[3][u];
            }
#pragma unroll
            for (int s = 0; s < 4; s++) {
                asm("v_cvt_pk_bf16_f32 %0, %1, %2" : "=v"(D[s][0]) : "v"(s1[4*s+0]), "v"(s1[4*s+1]));
                asm("v_cvt_pk_bf16_f32 %0, %1, %2" : "=v"(D[s][1]) : "v"(s1[4*s+2]), "v"(s1[4*s+3]));
            }
#pragma unroll
            for (int u = 0; u < 2; u++) {
                asm volatile("v_permlane32_swap_b32 %0, %1" : "+v"(D[0][u]), "+v"(D[1][u]));
                asm volatile("v_permlane32_swap_b32 %0, %1" : "+v"(D[2][u]), "+v"(D[3][u]));
                pbw[2][u] = D[0][u]; pbw[2][u + 2] = D[1][u];
                pbw[3][u] = D[2][u]; pbw[3][u + 2] = D[3][u];
            }
        }

        // ---- PV: O[d][q] += V^T x P
        __builtin_amdgcn_s_setprio(1);
#pragma unroll
        for (int c = 0; c < 4; c++) {
            uintx4 pw; pw[0] = pbw[c][0]; pw[1] = pbw[c][1]; pw[2] = pbw[c][2]; pw[3] = pbw[c][3];
            short8 pf = __builtin_bit_cast(short8, pw);
            O0 = __builtin_amdgcn_mfma_f32_32x32x16_bf16(vf0[c], pf, O0, 0, 0, 0);
            O1 = __builtin_amdgcn_mfma_f32_32x32x16_bf16(vf1[c], pf, O1, 0, 0, 0);
        }
        __builtin_amdgcn_s_setprio(0);

        // ---- V-frags dead: issue next tile's V loads (fly under next QK^T+softmax)
#pragma unroll
        for (int c = 0; c < 4; c++) {
            vf0[c] = *reinterpret_cast<const short8*>(vbase + ktn + c * 16);
            vf1[c] = *reinterpret_cast<const short8*>(vbase2 + ktn + c * 16);
        }
        __builtin_amdgcn_sched_barrier(0);
    }

    // ================= combine across the 8 KV-splits (3-stage tree) =======
    l_r = l_r + __shfl_xor(l_r, 32);          // reduce l across hi halves
    if (hi == 0) mlm[w][j] = m_r;
    __syncthreads();
    float M = mlm[0][j];
#pragma unroll
    for (int ww = 1; ww < 8; ww++) M = fmaxf(M, mlm[ww][j]);
    float al = __builtin_amdgcn_exp2f((m_r - M) * CEXP);   // 0 for empty waves
#pragma unroll
    for (int t = 0; t < 16; t++) { O0[t] *= al; O1[t] *= al; }
    if (hi == 0) mll[w][j] = l_r * al;

    if (w >= 4) {
#pragma unroll
        for (int t = 0; t < 16; t++) {
            obuf[w - 4][lane][t]      = O0[t];
            obuf[w - 4][lane][t + 16] = O1[t];
        }
    }
    __syncthreads();
    if (w < 4) {
#pragma unroll
        for (int t = 0; t < 16; t++) {
            O0[t] += obuf[w][lane][t];
            O1[t] += obuf[w][lane][t + 16];
        }
    }
    __syncthreads();
    if (w >= 2 && w < 4) {
#pragma unroll
        for (int t = 0; t < 16; t++) {
            obuf[w - 2][lane][t]      = O0[t];
            obuf[w - 2][lane][t + 16] = O1[t];
        }
    }
    __syncthreads();
    if (w < 2) {
#pragma unroll
        for (int t = 0; t < 16; t++) {
            O0[t] += obuf[w][lane][t];
            O1[t] += obuf[w][lane][t + 16];
        }
    }
    __syncthreads();
    if (w == 1) {
#pragma unroll
        for (int t = 0; t < 16; t++) {
            obuf[0][lane][t]      = O0[t];
            obuf[0][lane][t + 16] = O1[t];
        }
    }
    __syncthreads();
    if (w == 0) {
#pragma unroll
        for (int t = 0; t < 16; t++) {
            O0[t] += obuf[0][lane][t];
            O1[t] += obuf[0][lane][t + 16];
        }
        float lt = 0.f;
#pragma unroll
        for (int ww = 0; ww < 8; ww++) lt += mll[ww][j];
        int qrow = qrow0 + j;
        float qm = (qrow < qlen) ? (1.0f / lt) : 0.f;
        float* ob = out + (size_t)(b * 2048 + qrow) * 1024 + h * 64;
#pragma unroll
        for (int s = 0; s < 4; s++) {
            float4 oa, obv;
            oa.x = O0[4*s+0] * qm; oa.y = O0[4*s+1] * qm; oa.z = O0[4*s+2] * qm; oa.w = O0[4*s+3] * qm;
            obv.x = O1[4*s+0] * qm; obv.y = O1[4*s+1] * qm; obv.z = O1[4*s+2] * qm; obv.w = O1[4*s+3] * qm;
            *reinterpret_cast<float4*>(ob + 8 * s + 4 * hi) = oa;
            *reinterpret_cast<float4*>(ob + 32 + 8 * s + 4 * hi) = obv;
        }
    }
}

// ---------------------------------------------------------------------------
extern "C" void kernel_launch(void* const* d_in, const int* in_sizes, int n_in,
                              void* d_out, int out_size, void* d_ws, size_t ws_size,
                              hipStream_t stream)
{
    const float* Q_seq = (const float*)d_in[0];
    const float* K_seq = (const float*)d_in[1];
    const float* V_seq = (const float*)d_in[2];
    const int*   Q_len = (const int*)d_in[3];
    const int*   V_len = (const int*)d_in[4];
    const float* WQ    = (const float*)d_in[5];
    const float* WK    = (const float*)d_in[6];
    const float* WV    = (const float*)d_in[7];
    float* outp = (float*)d_out;

    // ws layout (bf16 elems): wt[3*1M] | q[4M] | k[4M] | vT[4M] | abf[3*4M]
    unsigned short* wsb = (unsigned short*)d_ws;
    unsigned short* wt  = wsb;
    unsigned short* qp  = wsb + (size_t)3 * 1048576u;
    unsigned short* kp  = qp + 4194304u;
    unsigned short* vTp = kp + 4194304u;
    unsigned short* abf = vTp + 4194304u;

    size_t need = ((size_t)3 * 1048576u + 3u * 4194304u + (size_t)3 * 4194304u) * 2u;
    bool precvt = ws_size >= need;

    wt_kernel<<<dim3(16, 16, 3), 256, 0, stream>>>(WQ, WK, WV, wt);
    if (precvt) {
        cvt_kernel<<<dim3(4096, 3), 256, 0, stream>>>(Q_seq, K_seq, V_seq, Q_len, V_len, abf);
        proj_kernel<true><<<dim3(8, 32, 3), 256, 0, stream>>>(
            Q_seq, K_seq, V_seq, abf, wt, Q_len, V_len, qp, kp, vTp);
    } else {
        proj_kernel<false><<<dim3(8, 32, 3), 256, 0, stream>>>(
            Q_seq, K_seq, V_seq, nullptr, wt, Q_len, V_len, qp, kp, vTp);
    }
    attn_kernel<<<dim3(2048), 512, 0, stream>>>(qp, kp, vTp, Q_len, V_len, outp);
}

// Round 9
// 104.072 us; speedup vs baseline: 1.3990x; 1.3990x over previous
//
#include <hip/hip_runtime.h>

// MultiHeadAttn: B=2, T=2048, D=1024, H=16, dh=64
// inputs: Q_seq,K_seq,V_seq [2,2048,1024] f32; Q_len,V_len [2,1] i32; WQ,WK,WV [1024,1024] f32
// output: [2,2048,1024] f32

using short8   = __attribute__((ext_vector_type(8))) short;
using floatx4  = __attribute__((ext_vector_type(4))) float;
using floatx16 = __attribute__((ext_vector_type(16))) float;
using uintx4   = __attribute__((ext_vector_type(4))) unsigned int;
using ushort4v = __attribute__((ext_vector_type(4))) unsigned short;

__device__ __forceinline__ unsigned short f2bf(float f) {
    unsigned int u = __builtin_bit_cast(unsigned int, f);
    u += 0x7fffu + ((u >> 16) & 1u);   // round-to-nearest-even
    return (unsigned short)(u >> 16);
}

// ---------------------------------------------------------------------------
// Kernel 0: fp32 -> bf16 convert of Q_seq/K_seq/V_seq rows that are needed.
// ---------------------------------------------------------------------------
__global__ __launch_bounds__(256) void cvt_kernel(
    const float* __restrict__ Qs, const float* __restrict__ Ks,
    const float* __restrict__ Vs, const int* __restrict__ Qlen,
    const int* __restrict__ Vlen, unsigned short* __restrict__ abf)
{
    int z = blockIdx.y, row = blockIdx.x;
    int b = row >> 11, rib = row & 2047;
    int ql = Qlen[b]; int vl = Vlen[b]; int vle = vl ? vl : 2048;
    int lim = (z == 0) ? ((ql + 127) & ~127) : ((vle + 127) & ~127);
    if (rib >= lim) return;
    const float* src = (z == 0) ? Qs : ((z == 1) ? Ks : Vs);
    int t = threadIdx.x;
    float4 v = *reinterpret_cast<const float4*>(src + (size_t)row * 1024 + t * 4);
    ushort4v o;
    o[0] = f2bf(v.x); o[1] = f2bf(v.y); o[2] = f2bf(v.z); o[3] = f2bf(v.w);
    *reinterpret_cast<ushort4v*>(abf + (size_t)z * 4194304u + (size_t)row * 1024 + t * 4) = o;
}

// ---------------------------------------------------------------------------
// Kernel 1: W [1024][1024] f32  ->  W^T [1024][1024] bf16 (z = 0,1,2)
// ---------------------------------------------------------------------------
__global__ __launch_bounds__(256) void wt_kernel(
    const float* __restrict__ W0, const float* __restrict__ W1,
    const float* __restrict__ W2, unsigned short* __restrict__ out)
{
    __shared__ float tile[64][65];
    int z = blockIdx.z;
    const float* W = (z == 0) ? W0 : ((z == 1) ? W1 : W2);
    unsigned short* O = out + (size_t)z * 1048576u;
    int r0 = blockIdx.y * 64, c0 = blockIdx.x * 64;
    int t = threadIdx.x;
#pragma unroll
    for (int i = 0; i < 16; i++) {
        int idx = t + i * 256; int r = idx >> 6, c = idx & 63;
        tile[r][c] = W[(size_t)(r0 + r) * 1024 + c0 + c];
    }
    __syncthreads();
#pragma unroll
    for (int i = 0; i < 16; i++) {
        int idx = t + i * 256; int c = idx >> 6, r = idx & 63;
        O[(size_t)(c0 + c) * 1024 + r0 + r] = f2bf(tile[r][c]);
    }
}

// ---------------------------------------------------------------------------
// Kernel 2: projection GEMM (unchanged)
// ---------------------------------------------------------------------------
template <bool PRECVT>
__global__ __launch_bounds__(256) void proj_kernel(
    const float* __restrict__ Qs, const float* __restrict__ Ks,
    const float* __restrict__ Vs, const unsigned short* __restrict__ abf,
    const unsigned short* __restrict__ wt,
    const int* __restrict__ Qlen, const int* __restrict__ Vlen,
    unsigned short* __restrict__ q, unsigned short* __restrict__ k,
    unsigned short* __restrict__ vT)
{
    __shared__ alignas(16) unsigned short As[128][72];
    __shared__ alignas(16) unsigned short Bs[128][72];

    int z = blockIdx.z;
    int tid = threadIdx.x;
    int m0 = blockIdx.y * 128, n0 = blockIdx.x * 128;
    int b = m0 >> 11, rib = m0 & 2047;
    int ql = Qlen[b]; int vl = Vlen[b]; int vle = vl ? vl : 2048;
    int lim = (z == 0) ? ((ql + 127) & ~127) : ((vle + 127) & ~127);
    if (rib >= lim) return;

    const float* Af = (z == 0) ? Qs : ((z == 1) ? Ks : Vs);
    const unsigned short* Ab = abf + (size_t)z * 4194304u;
    const unsigned short* Bt = wt + (size_t)z * 1048576u;

    int w = tid >> 6, lane = tid & 63, g = lane >> 4, lr = lane & 15;
    int wr = w >> 1, wc = w & 1;

    floatx4 acc[4][4];
#pragma unroll
    for (int m = 0; m < 4; m++)
#pragma unroll
        for (int n = 0; n < 4; n++) {
#pragma unroll
            for (int r = 0; r < 4; r++) acc[m][n][r] = 0.f;
        }

    int srow = tid >> 1, scol = (tid & 1) * 32;

    short8 pa[4], pb[4];
    float4 fa[8];

    if constexpr (PRECVT) {
#pragma unroll
        for (int i = 0; i < 4; i++)
            pa[i] = *reinterpret_cast<const short8*>(Ab + (size_t)(m0 + srow) * 1024 + scol + i * 8);
    } else {
#pragma unroll
        for (int i = 0; i < 8; i++)
            fa[i] = *reinterpret_cast<const float4*>(Af + (size_t)(m0 + srow) * 1024 + scol + i * 4);
    }
#pragma unroll
    for (int i = 0; i < 4; i++)
        pb[i] = *reinterpret_cast<const short8*>(Bt + (size_t)(n0 + srow) * 1024 + scol + i * 8);

    for (int kb = 0; kb < 1024; kb += 64) {
        __syncthreads();
        if constexpr (PRECVT) {
#pragma unroll
            for (int i = 0; i < 4; i++)
                *reinterpret_cast<short8*>(&As[srow][scol + i * 8]) = pa[i];
        } else {
#pragma unroll
            for (int i = 0; i < 4; i++) {
                short8 h;
                h[0] = (short)f2bf(fa[2*i].x);   h[1] = (short)f2bf(fa[2*i].y);
                h[2] = (short)f2bf(fa[2*i].z);   h[3] = (short)f2bf(fa[2*i].w);
                h[4] = (short)f2bf(fa[2*i+1].x); h[5] = (short)f2bf(fa[2*i+1].y);
                h[6] = (short)f2bf(fa[2*i+1].z); h[7] = (short)f2bf(fa[2*i+1].w);
                *reinterpret_cast<short8*>(&As[srow][scol + i * 8]) = h;
            }
        }
#pragma unroll
        for (int i = 0; i < 4; i++)
            *reinterpret_cast<short8*>(&Bs[srow][scol + i * 8]) = pb[i];
        __syncthreads();

        if (kb + 64 < 1024) {
            if constexpr (PRECVT) {
#pragma unroll
                for (int i = 0; i < 4; i++)
                    pa[i] = *reinterpret_cast<const short8*>(Ab + (size_t)(m0 + srow) * 1024 + kb + 64 + scol + i * 8);
            } else {
#pragma unroll
                for (int i = 0; i < 8; i++)
                    fa[i] = *reinterpret_cast<const float4*>(Af + (size_t)(m0 + srow) * 1024 + kb + 64 + scol + i * 4);
            }
#pragma unroll
            for (int i = 0; i < 4; i++)
                pb[i] = *reinterpret_cast<const short8*>(Bt + (size_t)(n0 + srow) * 1024 + kb + 64 + scol + i * 8);
        }

#pragma unroll
        for (int kc = 0; kc < 2; kc++) {
            short8 af[4], bf[4];
#pragma unroll
            for (int m = 0; m < 4; m++)
                af[m] = *reinterpret_cast<const short8*>(&As[wr * 64 + m * 16 + lr][kc * 32 + g * 8]);
#pragma unroll
            for (int n = 0; n < 4; n++)
                bf[n] = *reinterpret_cast<const short8*>(&Bs[wc * 64 + n * 16 + lr][kc * 32 + g * 8]);
#pragma unroll
            for (int m = 0; m < 4; m++)
#pragma unroll
                for (int n = 0; n < 4; n++)
                    acc[m][n] = __builtin_amdgcn_mfma_f32_16x16x32_bf16(af[m], bf[n], acc[m][n], 0, 0, 0);
        }
    }

    if (z < 2) {
        unsigned short* outp = (z == 0) ? q : k;
#pragma unroll
        for (int m = 0; m < 4; m++) {
            int row0 = m0 + wr * 64 + m * 16 + g * 4;
#pragma unroll
            for (int n = 0; n < 4; n++) {
                int col = n0 + wc * 64 + n * 16 + lr;
#pragma unroll
                for (int r = 0; r < 4; r++)
                    outp[(size_t)(row0 + r) * 1024 + col] = f2bf(acc[m][n][r]);
            }
        }
    } else {
#pragma unroll
        for (int m = 0; m < 4; m++) {
            int row0 = m0 + wr * 64 + m * 16 + g * 4;
            int bb = row0 >> 11, t0 = row0 & 2047;
#pragma unroll
            for (int n = 0; n < 4; n++) {
                int col = n0 + wc * 64 + n * 16 + lr;
                ushort4v pk;
#pragma unroll
                for (int r = 0; r < 4; r++) pk[r] = f2bf(acc[m][n][r]);
                *reinterpret_cast<ushort4v*>(vT + (size_t)(bb * 1024 + col) * 2048 + t0) = pk;
            }
        }
    }
}

// ---------------------------------------------------------------------------
// Kernel 3: flash attention, 32x32 swapped-QK, 8-way KV split.
// IDENTICAL to R8 except __launch_bounds__(512) with NO min-waves clause:
// R8's (512,4) forced VGPR=64 -> spill storm (WRITE_SIZE 188MB). Let the
// allocator use ~110 VGPR (R7 footprint); resources then allow 2 blocks/CU
// = 16 waves/CU resident, which is the occupancy split-8 was built for.
// ---------------------------------------------------------------------------
__global__ __launch_bounds__(512) void attn_kernel(
    const unsigned short* __restrict__ q, const unsigned short* __restrict__ k,
    const unsigned short* __restrict__ vT, const int* __restrict__ Qlen,
    const int* __restrict__ Vlen, float* __restrict__ out)
{
    __shared__ float obuf[4][64][33];   // 33792 B: O exchange
    __shared__ float mlm[8][33];        // per-wave m
    __shared__ float mll[8][33];        // per-wave l'

    int tid = threadIdx.x;
    int w = tid >> 6, lane = tid & 63;
    int j = lane & 31, hi = lane >> 5;

    int blk = blockIdx.x;
    int x = blk & 7, idx = blk >> 3;
    int bh = x + 8 * (idx >> 6), qtile = idx & 63;
    int b = bh >> 4, h = bh & 15;
    int qlen = Qlen[b]; int vl = Vlen[b]; int vle = vl ? vl : 2048;
    int qrow0 = qtile * 32;

    if (qrow0 >= qlen) {   // whole block masked -> zeros (block-uniform, pre-barrier)
        int zr = qrow0 + (tid >> 4);
        float* p = out + (size_t)(b * 2048 + zr) * 1024 + h * 64 + (tid & 15) * 4;
        float4 z4; z4.x = 0.f; z4.y = 0.f; z4.z = 0.f; z4.w = 0.f;
        *reinterpret_cast<float4*>(p) = z4;
        return;
    }

    int nt = (vle + 63) >> 6;                      // # 64-key tiles (>= 1)
    int ntw = (nt > w) ? ((nt - w + 7) >> 3) : 0;  // tiles for this wave

    const unsigned short* kbase = k + (size_t)(b * 2048) * 1024 + h * 64 + hi * 8;
    const unsigned short* vbase = vT + (size_t)(b * 1024 + h * 64 + j) * 2048 + hi * 8;
    const unsigned short* vbase2 = vbase + 32 * 2048;

    // ---- initial fragment loads (tile w, clamped)
    short8 kf0[4], kf1[4], vf0[4], vf1[4];
    {
        int t0 = (w < nt) ? w : (nt - 1);
        int kt = t0 << 6;
        const unsigned short* kr0 = kbase + (size_t)(kt + j) * 1024;
        const unsigned short* kr1 = kbase + (size_t)(kt + 32 + j) * 1024;
#pragma unroll
        for (int c = 0; c < 4; c++) {
            kf0[c] = *reinterpret_cast<const short8*>(kr0 + c * 16);
            kf1[c] = *reinterpret_cast<const short8*>(kr1 + c * 16);
            vf0[c] = *reinterpret_cast<const short8*>(vbase + kt + c * 16);
            vf1[c] = *reinterpret_cast<const short8*>(vbase2 + kt + c * 16);
        }
    }
    __builtin_amdgcn_sched_barrier(0);

    // Q fragments: B-operand, lane holds Q[q=qrow0+j][c*16 + hi*8 + 0..7]
    short8 qf[4];
    {
        const unsigned short* qp = q + (size_t)(b * 2048 + qrow0 + j) * 1024 + h * 64 + hi * 8;
#pragma unroll
        for (int c = 0; c < 4; c++) qf[c] = *reinterpret_cast<const short8*>(qp + c * 16);
    }

    floatx16 O0, O1;
#pragma unroll
    for (int t = 0; t < 16; t++) { O0[t] = 0.f; O1[t] = 0.f; }
    float m_r = -3.0e38f, l_r = 0.f;

    const float CEXP = 0.18033688011112042f;   // 0.125 * log2(e)

    for (int m = 0; m < ntw; ++m) {
        int tix = w + 8 * m;
        int kt = tix << 6;
        int tnx = tix + 8; if (tnx >= nt) tnx = nt - 1;   // clamped prefetch target
        int ktn = tnx << 6;

        // ---- QK^T (swapped): col=lane&31=q, row=(t&3)+8*(t>>2)+4*hi
        floatx16 s0, s1;
#pragma unroll
        for (int t = 0; t < 16; t++) { s0[t] = 0.f; s1[t] = 0.f; }
        __builtin_amdgcn_s_setprio(1);
#pragma unroll
        for (int c = 0; c < 4; c++) {
            s0 = __builtin_amdgcn_mfma_f32_32x32x16_bf16(kf0[c], qf[c], s0, 0, 0, 0);
            s1 = __builtin_amdgcn_mfma_f32_32x32x16_bf16(kf1[c], qf[c], s1, 0, 0, 0);
        }
        __builtin_amdgcn_s_setprio(0);

        // ---- K-frags are dead: issue next tile's K loads NOW (fly under softmax+PV)
        {
            const unsigned short* kr0 = kbase + (size_t)(ktn + j) * 1024;
            const unsigned short* kr1 = kbase + (size_t)(ktn + 32 + j) * 1024;
#pragma unroll
            for (int c = 0; c < 4; c++) {
                kf0[c] = *reinterpret_cast<const short8*>(kr0 + c * 16);
                kf1[c] = *reinterpret_cast<const short8*>(kr1 + c * 16);
            }
        }
        __builtin_amdgcn_sched_barrier(0);

        if (kt + 64 > vle) {   // boundary tile: mask keys >= vle
#pragma unroll
            for (int t = 0; t < 16; t++) {
                int kl = (t & 3) + 8 * (t >> 2) + 4 * hi;
                if (kt + kl >= vle)      s0[t] = -8.0e12f;
                if (kt + 32 + kl >= vle) s1[t] = -8.0e12f;
            }
        }

        // ---- online softmax
        float mx = s0[0];
#pragma unroll
        for (int t = 1; t < 16; t++) mx = fmaxf(mx, s0[t]);
#pragma unroll
        for (int t = 0; t < 16; t++) mx = fmaxf(mx, s1[t]);
        float lm = fmaxf(mx, __shfl_xor(mx, 32));

        if (__any(lm > m_r + 64.f)) {
            float mn = fmaxf(m_r, lm);
            float al = __builtin_amdgcn_exp2f((m_r - mn) * CEXP);
            m_r = mn;
            l_r *= al;
#pragma unroll
            for (int t = 0; t < 16; t++) { O0[t] *= al; O1[t] *= al; }
        }
        float nm = -m_r * CEXP;
#pragma unroll
        for (int t = 0; t < 16; t++) {
            s0[t] = __builtin_amdgcn_exp2f(fmaf(s0[t], CEXP, nm));
            s1[t] = __builtin_amdgcn_exp2f(fmaf(s1[t], CEXP, nm));
        }
        float rs = 0.f;
#pragma unroll
        for (int t = 0; t < 16; t++) rs += s0[t] + s1[t];
        l_r += rs;

        // ---- P -> bf16 B-fragments via cvt_pk + permlane32_swap
        unsigned int pbw[4][4];
        {
            unsigned int D[4][2];
#pragma unroll
            for (int s = 0; s < 4; s++) {
                asm("v_cvt_pk_bf16_f32 %0, %1, %2" : "=v"(D[s][0]) : "v"(s0[4*s+0]), "v"(s0[4*s+1]));
                asm("v_cvt_pk_bf16_f32 %0, %1, %2" : "=v"(D[s][1]) : "v"(s0[4*s+2]), "v"(s0[4*s+3]));
            }
#pragma unroll
            for (int u = 0; u < 2; u++) {
                asm volatile("v_permlane32_swap_b32 %0, %1" : "+v"(D[0][u]), "+v"(D[1][u]));
                asm volatile("v_permlane32_swap_b32 %0, %1" : "+v"(D[2][u]), "+v"(D[3][u]));
                pbw[0][u] = D[0][u]; pbw[0][u + 2] = D[1][u];
                pbw[1][u] = D[2][u]; pbw[1][u + 2] = D[3][u];
            }
#pragma unroll
            for (int s = 0; s < 4; s++) {
                asm("v_cvt_pk_bf16_f32 %0, %1, %2" : "=v"(D[s][0]) : "v"(s1[4*s+0]), "v"(s1[4*s+1]));
                asm("v_cvt_pk_bf16_f32 %0, %1, %2" : "=v"(D[s][1]) : "v"(s1[4*s+2]), "v"(s1[4*s+3]));
            }
#pragma unroll
            for (int u = 0; u < 2; u++) {
                asm volatile("v_permlane32_swap_b32 %0, %1" : "+v"(D[0][u]), "+v"(D[1][u]));
                asm volatile("v_permlane32_swap_b32 %0, %1" : "+v"(D[2][u]), "+v"(D[3][u]));
                pbw[2][u] = D[0][u]; pbw[2][u + 2] = D[1][u];
                pbw[3][u] = D[2][u]; pbw[3][u + 2] = D[3][u];
            }
        }

        // ---- PV: O[d][q] += V^T x P
        __builtin_amdgcn_s_setprio(1);
#pragma unroll
        for (int c = 0; c < 4; c++) {
            uintx4 pw; pw[0] = pbw[c][0]; pw[1] = pbw[c][1]; pw[2] = pbw[c][2]; pw[3] = pbw[c][3];
            short8 pf = __builtin_bit_cast(short8, pw);
            O0 = __builtin_amdgcn_mfma_f32_32x32x16_bf16(vf0[c], pf, O0, 0, 0, 0);
            O1 = __builtin_amdgcn_mfma_f32_32x32x16_bf16(vf1[c], pf, O1, 0, 0, 0);
        }
        __builtin_amdgcn_s_setprio(0);

        // ---- V-frags dead: issue next tile's V loads (fly under next QK^T+softmax)
#pragma unroll
        for (int c = 0; c < 4; c++) {
            vf0[c] = *reinterpret_cast<const short8*>(vbase + ktn + c * 16);
            vf1[c] = *reinterpret_cast<const short8*>(vbase2 + ktn + c * 16);
        }
        __builtin_amdgcn_sched_barrier(0);
    }

    // ================= combine across the 8 KV-splits (3-stage tree) =======
    l_r = l_r + __shfl_xor(l_r, 32);          // reduce l across hi halves
    if (hi == 0) mlm[w][j] = m_r;
    __syncthreads();
    float M = mlm[0][j];
#pragma unroll
    for (int ww = 1; ww < 8; ww++) M = fmaxf(M, mlm[ww][j]);
    float al = __builtin_amdgcn_exp2f((m_r - M) * CEXP);   // 0 for empty waves
#pragma unroll
    for (int t = 0; t < 16; t++) { O0[t] *= al; O1[t] *= al; }
    if (hi == 0) mll[w][j] = l_r * al;

    if (w >= 4) {
#pragma unroll
        for (int t = 0; t < 16; t++) {
            obuf[w - 4][lane][t]      = O0[t];
            obuf[w - 4][lane][t + 16] = O1[t];
        }
    }
    __syncthreads();
    if (w < 4) {
#pragma unroll
        for (int t = 0; t < 16; t++) {
            O0[t] += obuf[w][lane][t];
            O1[t] += obuf[w][lane][t + 16];
        }
    }
    __syncthreads();
    if (w >= 2 && w < 4) {
#pragma unroll
        for (int t = 0; t < 16; t++) {
            obuf[w - 2][lane][t]      = O0[t];
            obuf[w - 2][lane][t + 16] = O1[t];
        }
    }
    __syncthreads();
    if (w < 2) {
#pragma unroll
        for (int t = 0; t < 16; t++) {
            O0[t] += obuf[w][lane][t];
            O1[t] += obuf[w][lane][t + 16];
        }
    }
    __syncthreads();
    if (w == 1) {
#pragma unroll
        for (int t = 0; t < 16; t++) {
            obuf[0][lane][t]      = O0[t];
            obuf[0][lane][t + 16] = O1[t];
        }
    }
    __syncthreads();
    if (w == 0) {
#pragma unroll
        for (int t = 0; t < 16; t++) {
            O0[t] += obuf[0][lane][t];
            O1[t] += obuf[0][lane][t + 16];
        }
        float lt = 0.f;
#pragma unroll
        for (int ww = 0; ww < 8; ww++) lt += mll[ww][j];
        int qrow = qrow0 + j;
        float qm = (qrow < qlen) ? (1.0f / lt) : 0.f;
        float* ob = out + (size_t)(b * 2048 + qrow) * 1024 + h * 64;
#pragma unroll
        for (int s = 0; s < 4; s++) {
            float4 oa, obv;
            oa.x = O0[4*s+0] * qm; oa.y = O0[4*s+1] * qm; oa.z = O0[4*s+2] * qm; oa.w = O0[4*s+3] * qm;
            obv.x = O1[4*s+0] * qm; obv.y = O1[4*s+1] * qm; obv.z = O1[4*s+2] * qm; obv.w = O1[4*s+3] * qm;
            *reinterpret_cast<float4*>(ob + 8 * s + 4 * hi) = oa;
            *reinterpret_cast<float4*>(ob + 32 + 8 * s + 4 * hi) = obv;
        }
    }
}

// ---------------------------------------------------------------------------
extern "C" void kernel_launch(void* const* d_in, const int* in_sizes, int n_in,
                              void* d_out, int out_size, void* d_ws, size_t ws_size,
                              hipStream_t stream)
{
    const float* Q_seq = (const float*)d_in[0];
    const float* K_seq = (const float*)d_in[1];
    const float* V_seq = (const float*)d_in[2];
    const int*   Q_len = (const int*)d_in[3];
    const int*   V_len = (const int*)d_in[4];
    const float* WQ    = (const float*)d_in[5];
    const float* WK    = (const float*)d_in[6];
    const float* WV    = (const float*)d_in[7];
    float* outp = (float*)d_out;

    // ws layout (bf16 elems): wt[3*1M] | q[4M] | k[4M] | vT[4M] | abf[3*4M]
    unsigned short* wsb = (unsigned short*)d_ws;
    unsigned short* wt  = wsb;
    unsigned short* qp  = wsb + (size_t)3 * 1048576u;
    unsigned short* kp  = qp + 4194304u;
    unsigned short* vTp = kp + 4194304u;
    unsigned short* abf = vTp + 4194304u;

    size_t need = ((size_t)3 * 1048576u + 3u * 4194304u + (size_t)3 * 4194304u) * 2u;
    bool precvt = ws_size >= need;

    wt_kernel<<<dim3(16, 16, 3), 256, 0, stream>>>(WQ, WK, WV, wt);
    if (precvt) {
        cvt_kernel<<<dim3(4096, 3), 256, 0, stream>>>(Q_seq, K_seq, V_seq, Q_len, V_len, abf);
        proj_kernel<true><<<dim3(8, 32, 3), 256, 0, stream>>>(
            Q_seq, K_seq, V_seq, abf, wt, Q_len, V_len, qp, kp, vTp);
    } else {
        proj_kernel<false><<<dim3(8, 32, 3), 256, 0, stream>>>(
            Q_seq, K_seq, V_seq, nullptr, wt, Q_len, V_len, qp, kp, vTp);
    }
    attn_kernel<<<dim3(2048), 512, 0, stream>>>(qp, kp, vTp, Q_len, V_len, outp);
}

// Round 10
// 84.302 us; speedup vs baseline: 1.7271x; 1.2345x over previous
//
#include <hip/hip_runtime.h>

// MultiHeadAttn: B=2, T=2048, D=1024, H=16, dh=64
// inputs: Q_seq,K_seq,V_seq [2,2048,1024] f32; Q_len,V_len [2,1] i32; WQ,WK,WV [1024,1024] f32
// output: [2,2048,1024] f32
//
// R10 change vs R7 (best known): PER-HEAD layouts for q/k/v so attention's
// fragment gathers hit a small L1-resident window:
//   qh,kh: [b][h][t][64]            (row 128B; 32-key K-window = 4KB)
//   vh:    [b][h][tile][d=64][k=64] (8KB contiguous per 64-key tile)
// Attn kernel structure = R7 verbatim (split-2, no-barrier reg-direct loop).

using short8   = __attribute__((ext_vector_type(8))) short;
using floatx4  = __attribute__((ext_vector_type(4))) float;
using floatx16 = __attribute__((ext_vector_type(16))) float;
using uintx4   = __attribute__((ext_vector_type(4))) unsigned int;
using ushort4v = __attribute__((ext_vector_type(4))) unsigned short;

__device__ __forceinline__ unsigned short f2bf(float f) {
    unsigned int u = __builtin_bit_cast(unsigned int, f);
    u += 0x7fffu + ((u >> 16) & 1u);   // round-to-nearest-even
    return (unsigned short)(u >> 16);
}

// ---------------------------------------------------------------------------
// Kernel 0: fp32 -> bf16 convert of Q_seq/K_seq/V_seq rows that are needed.
// ---------------------------------------------------------------------------
__global__ __launch_bounds__(256) void cvt_kernel(
    const float* __restrict__ Qs, const float* __restrict__ Ks,
    const float* __restrict__ Vs, const int* __restrict__ Qlen,
    const int* __restrict__ Vlen, unsigned short* __restrict__ abf)
{
    int z = blockIdx.y, row = blockIdx.x;
    int b = row >> 11, rib = row & 2047;
    int ql = Qlen[b]; int vl = Vlen[b]; int vle = vl ? vl : 2048;
    int lim = (z == 0) ? ((ql + 127) & ~127) : ((vle + 127) & ~127);
    if (rib >= lim) return;
    const float* src = (z == 0) ? Qs : ((z == 1) ? Ks : Vs);
    int t = threadIdx.x;
    float4 v = *reinterpret_cast<const float4*>(src + (size_t)row * 1024 + t * 4);
    ushort4v o;
    o[0] = f2bf(v.x); o[1] = f2bf(v.y); o[2] = f2bf(v.z); o[3] = f2bf(v.w);
    *reinterpret_cast<ushort4v*>(abf + (size_t)z * 4194304u + (size_t)row * 1024 + t * 4) = o;
}

// ---------------------------------------------------------------------------
// Kernel 1: W [1024][1024] f32  ->  W^T [1024][1024] bf16 (z = 0,1,2)
// ---------------------------------------------------------------------------
__global__ __launch_bounds__(256) void wt_kernel(
    const float* __restrict__ W0, const float* __restrict__ W1,
    const float* __restrict__ W2, unsigned short* __restrict__ out)
{
    __shared__ float tile[64][65];
    int z = blockIdx.z;
    const float* W = (z == 0) ? W0 : ((z == 1) ? W1 : W2);
    unsigned short* O = out + (size_t)z * 1048576u;
    int r0 = blockIdx.y * 64, c0 = blockIdx.x * 64;
    int t = threadIdx.x;
#pragma unroll
    for (int i = 0; i < 16; i++) {
        int idx = t + i * 256; int r = idx >> 6, c = idx & 63;
        tile[r][c] = W[(size_t)(r0 + r) * 1024 + c0 + c];
    }
    __syncthreads();
#pragma unroll
    for (int i = 0; i < 16; i++) {
        int idx = t + i * 256; int c = idx >> 6, r = idx & 63;
        O[(size_t)(c0 + c) * 1024 + r0 + r] = f2bf(tile[r][c]);
    }
}

// ---------------------------------------------------------------------------
// Kernel 2: projection GEMM. Core unchanged; epilogue writes PER-HEAD layouts.
// ---------------------------------------------------------------------------
template <bool PRECVT>
__global__ __launch_bounds__(256) void proj_kernel(
    const float* __restrict__ Qs, const float* __restrict__ Ks,
    const float* __restrict__ Vs, const unsigned short* __restrict__ abf,
    const unsigned short* __restrict__ wt,
    const int* __restrict__ Qlen, const int* __restrict__ Vlen,
    unsigned short* __restrict__ q, unsigned short* __restrict__ k,
    unsigned short* __restrict__ vh)
{
    __shared__ alignas(16) unsigned short As[128][72];
    __shared__ alignas(16) unsigned short Bs[128][72];

    int z = blockIdx.z;
    int tid = threadIdx.x;
    int m0 = blockIdx.y * 128, n0 = blockIdx.x * 128;
    int b = m0 >> 11, rib = m0 & 2047;
    int ql = Qlen[b]; int vl = Vlen[b]; int vle = vl ? vl : 2048;
    int lim = (z == 0) ? ((ql + 127) & ~127) : ((vle + 127) & ~127);
    if (rib >= lim) return;

    const float* Af = (z == 0) ? Qs : ((z == 1) ? Ks : Vs);
    const unsigned short* Ab = abf + (size_t)z * 4194304u;
    const unsigned short* Bt = wt + (size_t)z * 1048576u;

    int w = tid >> 6, lane = tid & 63, g = lane >> 4, lr = lane & 15;
    int wr = w >> 1, wc = w & 1;

    floatx4 acc[4][4];
#pragma unroll
    for (int m = 0; m < 4; m++)
#pragma unroll
        for (int n = 0; n < 4; n++) {
#pragma unroll
            for (int r = 0; r < 4; r++) acc[m][n][r] = 0.f;
        }

    int srow = tid >> 1, scol = (tid & 1) * 32;

    short8 pa[4], pb[4];
    float4 fa[8];

    if constexpr (PRECVT) {
#pragma unroll
        for (int i = 0; i < 4; i++)
            pa[i] = *reinterpret_cast<const short8*>(Ab + (size_t)(m0 + srow) * 1024 + scol + i * 8);
    } else {
#pragma unroll
        for (int i = 0; i < 8; i++)
            fa[i] = *reinterpret_cast<const float4*>(Af + (size_t)(m0 + srow) * 1024 + scol + i * 4);
    }
#pragma unroll
    for (int i = 0; i < 4; i++)
        pb[i] = *reinterpret_cast<const short8*>(Bt + (size_t)(n0 + srow) * 1024 + scol + i * 8);

    for (int kb = 0; kb < 1024; kb += 64) {
        __syncthreads();
        if constexpr (PRECVT) {
#pragma unroll
            for (int i = 0; i < 4; i++)
                *reinterpret_cast<short8*>(&As[srow][scol + i * 8]) = pa[i];
        } else {
#pragma unroll
            for (int i = 0; i < 4; i++) {
                short8 h;
                h[0] = (short)f2bf(fa[2*i].x);   h[1] = (short)f2bf(fa[2*i].y);
                h[2] = (short)f2bf(fa[2*i].z);   h[3] = (short)f2bf(fa[2*i].w);
                h[4] = (short)f2bf(fa[2*i+1].x); h[5] = (short)f2bf(fa[2*i+1].y);
                h[6] = (short)f2bf(fa[2*i+1].z); h[7] = (short)f2bf(fa[2*i+1].w);
                *reinterpret_cast<short8*>(&As[srow][scol + i * 8]) = h;
            }
        }
#pragma unroll
        for (int i = 0; i < 4; i++)
            *reinterpret_cast<short8*>(&Bs[srow][scol + i * 8]) = pb[i];
        __syncthreads();

        if (kb + 64 < 1024) {
            if constexpr (PRECVT) {
#pragma unroll
                for (int i = 0; i < 4; i++)
                    pa[i] = *reinterpret_cast<const short8*>(Ab + (size_t)(m0 + srow) * 1024 + kb + 64 + scol + i * 8);
            } else {
#pragma unroll
                for (int i = 0; i < 8; i++)
                    fa[i] = *reinterpret_cast<const float4*>(Af + (size_t)(m0 + srow) * 1024 + kb + 64 + scol + i * 4);
            }
#pragma unroll
            for (int i = 0; i < 4; i++)
                pb[i] = *reinterpret_cast<const short8*>(Bt + (size_t)(n0 + srow) * 1024 + kb + 64 + scol + i * 8);
        }

#pragma unroll
        for (int kc = 0; kc < 2; kc++) {
            short8 af[4], bf[4];
#pragma unroll
            for (int m = 0; m < 4; m++)
                af[m] = *reinterpret_cast<const short8*>(&As[wr * 64 + m * 16 + lr][kc * 32 + g * 8]);
#pragma unroll
            for (int n = 0; n < 4; n++)
                bf[n] = *reinterpret_cast<const short8*>(&Bs[wc * 64 + n * 16 + lr][kc * 32 + g * 8]);
#pragma unroll
            for (int m = 0; m < 4; m++)
#pragma unroll
                for (int n = 0; n < 4; n++)
                    acc[m][n] = __builtin_amdgcn_mfma_f32_16x16x32_bf16(af[m], bf[n], acc[m][n], 0, 0, 0);
        }
    }

    // epilogue -> per-head layouts
    if (z < 2) {
        unsigned short* outp = (z == 0) ? q : k;
#pragma unroll
        for (int m = 0; m < 4; m++) {
            int row0 = m0 + wr * 64 + m * 16 + g * 4;
            int tg0 = row0 & 2047;
#pragma unroll
            for (int n = 0; n < 4; n++) {
                int col = n0 + wc * 64 + n * 16 + lr;
                int hh = col >> 6, dd = col & 63;
                size_t base = ((size_t)(b * 16 + hh) * 2048 + tg0) * 64 + dd;
#pragma unroll
                for (int r = 0; r < 4; r++)
                    outp[base + (size_t)r * 64] = f2bf(acc[m][n][r]);
            }
        }
    } else {
#pragma unroll
        for (int m = 0; m < 4; m++) {
            int row0 = m0 + wr * 64 + m * 16 + g * 4;
            int tg = row0 & 2047;                 // 4-aligned
#pragma unroll
            for (int n = 0; n < 4; n++) {
                int col = n0 + wc * 64 + n * 16 + lr;
                int hh = col >> 6, dd = col & 63;
                ushort4v pk;
#pragma unroll
                for (int r = 0; r < 4; r++) pk[r] = f2bf(acc[m][n][r]);
                // vh[b][h][tile=tg>>6][d=dd][key=tg&63], 4 consecutive keys
                size_t addr = ((size_t)(b * 16 + hh) * 32 + (tg >> 6)) * 4096
                            + (size_t)dd * 64 + (tg & 63);
                *reinterpret_cast<ushort4v*>(vh + addr) = pk;
            }
        }
    }
}

// ---------------------------------------------------------------------------
// Kernel 3: flash attention — R7 structure verbatim, per-head layouts.
// 128 thr = 2 waves sharing 32 q rows; wave w does KV tiles {w, w+2, ...};
// no LDS / no barriers in the loop; reg-direct fragments; sched_barrier-pinned
// next-tile loads; tiny-LDS combine at the end.
// ---------------------------------------------------------------------------
__global__ __launch_bounds__(128, 2) void attn_kernel(
    const unsigned short* __restrict__ q, const unsigned short* __restrict__ k,
    const unsigned short* __restrict__ vh, const int* __restrict__ Qlen,
    const int* __restrict__ Vlen, float* __restrict__ out)
{
    __shared__ float obuf[64][33];     // 8448 B, O exchange
    __shared__ float mlm[2][33];       // per-wave m
    __shared__ float mll[2][33];       // per-wave l'

    int tid = threadIdx.x;
    int w = tid >> 6, lane = tid & 63;
    int j = lane & 31, hi = lane >> 5;

    int blk = blockIdx.x;
    int x = blk & 7, idx = blk >> 3;
    int bh = x + 8 * (idx >> 6), qtile = idx & 63;
    int b = bh >> 4, h = bh & 15;
    int qlen = Qlen[b]; int vl = Vlen[b]; int vle = vl ? vl : 2048;
    int qrow0 = qtile * 32;

    if (qrow0 >= qlen) {   // whole block masked -> zeros (block-uniform, no barriers crossed)
        int zr = qrow0 + (tid >> 2);
        float* p = out + (size_t)(b * 2048 + zr) * 1024 + h * 64 + (tid & 3) * 16;
        float4 z4; z4.x = 0.f; z4.y = 0.f; z4.z = 0.f; z4.w = 0.f;
#pragma unroll
        for (int s = 0; s < 4; s++) *reinterpret_cast<float4*>(p + 4 * s) = z4;
        return;
    }

    int nt = (vle + 63) >> 6;               // # 64-key tiles (>= 1)
    int ntw = (nt - w + 1) >> 1;            // tiles for this wave

    // per-head bases (each head block = 131072 bf16)
    const unsigned short* khb = k + (size_t)(b * 16 + h) * 131072u + hi * 8;
    const unsigned short* vhb = vh + (size_t)(b * 16 + h) * 131072u + hi * 8;

    // ---- initial fragment loads (tile w, clamped)
    short8 kf0[4], kf1[4], vf0[4], vf1[4];
    {
        int t0 = (w < nt) ? w : (nt - 1);
        int kt = t0 << 6;
        const unsigned short* kr0 = khb + (size_t)(kt + j) * 64;
        const unsigned short* kr1 = khb + (size_t)(kt + 32 + j) * 64;
        const unsigned short* vt0 = vhb + (size_t)t0 * 4096 + j * 64;
#pragma unroll
        for (int c = 0; c < 4; c++) {
            kf0[c] = *reinterpret_cast<const short8*>(kr0 + c * 16);
            kf1[c] = *reinterpret_cast<const short8*>(kr1 + c * 16);
            vf0[c] = *reinterpret_cast<const short8*>(vt0 + c * 16);
            vf1[c] = *reinterpret_cast<const short8*>(vt0 + 2048 + c * 16);
        }
    }
    __builtin_amdgcn_sched_barrier(0);

    // Q fragments: B-operand, lane holds Q[q=qrow0+j][c*16 + hi*8 + 0..7]
    short8 qf[4];
    {
        const unsigned short* qp = q + (size_t)(b * 16 + h) * 131072u
                                     + (size_t)(qrow0 + j) * 64 + hi * 8;
#pragma unroll
        for (int c = 0; c < 4; c++) qf[c] = *reinterpret_cast<const short8*>(qp + c * 16);
    }

    floatx16 O0, O1;
#pragma unroll
    for (int t = 0; t < 16; t++) { O0[t] = 0.f; O1[t] = 0.f; }
    float m_r = -3.0e38f, l_r = 0.f;

    const float CEXP = 0.18033688011112042f;   // 0.125 * log2(e)

    for (int m = 0; m < ntw; ++m) {
        int tix = w + 2 * m;
        int kt = tix << 6;
        int tnx = tix + 2; if (tnx >= nt) tnx = nt - 1;   // clamped prefetch target
        int ktn = tnx << 6;

        // ---- QK^T (swapped): col=lane&31=q, row=(t&3)+8*(t>>2)+4*hi
        floatx16 s0, s1;
#pragma unroll
        for (int t = 0; t < 16; t++) { s0[t] = 0.f; s1[t] = 0.f; }
#pragma unroll
        for (int c = 0; c < 4; c++) {
            s0 = __builtin_amdgcn_mfma_f32_32x32x16_bf16(kf0[c], qf[c], s0, 0, 0, 0);
            s1 = __builtin_amdgcn_mfma_f32_32x32x16_bf16(kf1[c], qf[c], s1, 0, 0, 0);
        }

        // ---- K-frags are dead: issue next tile's K loads NOW (fly under softmax+PV)
        {
            const unsigned short* kr0 = khb + (size_t)(ktn + j) * 64;
            const unsigned short* kr1 = khb + (size_t)(ktn + 32 + j) * 64;
#pragma unroll
            for (int c = 0; c < 4; c++) {
                kf0[c] = *reinterpret_cast<const short8*>(kr0 + c * 16);
                kf1[c] = *reinterpret_cast<const short8*>(kr1 + c * 16);
            }
        }
        __builtin_amdgcn_sched_barrier(0);

        if (kt + 64 > vle) {   // boundary tile: mask keys >= vle
#pragma unroll
            for (int t = 0; t < 16; t++) {
                int kl = (t & 3) + 8 * (t >> 2) + 4 * hi;
                if (kt + kl >= vle)      s0[t] = -8.0e12f;
                if (kt + 32 + kl >= vle) s1[t] = -8.0e12f;
            }
        }

        // ---- online softmax
        float mx = s0[0];
#pragma unroll
        for (int t = 1; t < 16; t++) mx = fmaxf(mx, s0[t]);
#pragma unroll
        for (int t = 0; t < 16; t++) mx = fmaxf(mx, s1[t]);
        float lm = fmaxf(mx, __shfl_xor(mx, 32));

        if (__any(lm > m_r + 64.f)) {
            float mn = fmaxf(m_r, lm);
            float al = __builtin_amdgcn_exp2f((m_r - mn) * CEXP);
            m_r = mn;
            l_r *= al;
#pragma unroll
            for (int t = 0; t < 16; t++) { O0[t] *= al; O1[t] *= al; }
        }
        float nm = -m_r * CEXP;
#pragma unroll
        for (int t = 0; t < 16; t++) {
            s0[t] = __builtin_amdgcn_exp2f(fmaf(s0[t], CEXP, nm));
            s1[t] = __builtin_amdgcn_exp2f(fmaf(s1[t], CEXP, nm));
        }
        float rs = 0.f;
#pragma unroll
        for (int t = 0; t < 16; t++) rs += s0[t] + s1[t];
        l_r += rs;

        // ---- P -> bf16 B-fragments via cvt_pk + permlane32_swap
        unsigned int pbw[4][4];
        {
            unsigned int D[4][2];
#pragma unroll
            for (int s = 0; s < 4; s++) {
                asm("v_cvt_pk_bf16_f32 %0, %1, %2" : "=v"(D[s][0]) : "v"(s0[4*s+0]), "v"(s0[4*s+1]));
                asm("v_cvt_pk_bf16_f32 %0, %1, %2" : "=v"(D[s][1]) : "v"(s0[4*s+2]), "v"(s0[4*s+3]));
            }
#pragma unroll
            for (int u = 0; u < 2; u++) {
                asm volatile("v_permlane32_swap_b32 %0, %1" : "+v"(D[0][u]), "+v"(D[1][u]));
                asm volatile("v_permlane32_swap_b32 %0, %1" : "+v"(D[2][u]), "+v"(D[3][u]));
                pbw[0][u] = D[0][u]; pbw[0][u + 2] = D[1][u];
                pbw[1][u] = D[2][u]; pbw[1][u + 2] = D[3][u];
            }
#pragma unroll
            for (int s = 0; s < 4; s++) {
                asm("v_cvt_pk_bf16_f32 %0, %1, %2" : "=v"(D[s][0]) : "v"(s1[4*s+0]), "v"(s1[4*s+1]));
                asm("v_cvt_pk_bf16_f32 %0, %1, %2" : "=v"(D[s][1]) : "v"(s1[4*s+2]), "v"(s1[4*s+3]));
            }
#pragma unroll
            for (int u = 0; u < 2; u++) {
                asm volatile("v_permlane32_swap_b32 %0, %1" : "+v"(D[0][u]), "+v"(D[1][u]));
                asm volatile("v_permlane32_swap_b32 %0, %1" : "+v"(D[2][u]), "+v"(D[3][u]));
                pbw[2][u] = D[0][u]; pbw[2][u + 2] = D[1][u];
                pbw[3][u] = D[2][u]; pbw[3][u + 2] = D[3][u];
            }
        }

        // ---- PV: O[d][q] += V^T x P
#pragma unroll
        for (int c = 0; c < 4; c++) {
            uintx4 pw; pw[0] = pbw[c][0]; pw[1] = pbw[c][1]; pw[2] = pbw[c][2]; pw[3] = pbw[c][3];
            short8 pf = __builtin_bit_cast(short8, pw);
            O0 = __builtin_amdgcn_mfma_f32_32x32x16_bf16(vf0[c], pf, O0, 0, 0, 0);
            O1 = __builtin_amdgcn_mfma_f32_32x32x16_bf16(vf1[c], pf, O1, 0, 0, 0);
        }

        // ---- V-frags dead: issue next tile's V loads (fly under next QK^T+softmax)
        {
            const unsigned short* vt = vhb + (size_t)tnx * 4096 + j * 64;
#pragma unroll
            for (int c = 0; c < 4; c++) {
                vf0[c] = *reinterpret_cast<const short8*>(vt + c * 16);
                vf1[c] = *reinterpret_cast<const short8*>(vt + 2048 + c * 16);
            }
        }
        __builtin_amdgcn_sched_barrier(0);
    }

    // ================= combine across the 2 KV-splits ======================
    l_r = l_r + __shfl_xor(l_r, 32);          // reduce l across hi halves
    if (hi == 0) mlm[w][j] = m_r;
    __syncthreads();
    float M = fmaxf(mlm[0][j], mlm[1][j]);
    float al = __builtin_amdgcn_exp2f((m_r - M) * CEXP);   // 0 for empty wave
#pragma unroll
    for (int t = 0; t < 16; t++) { O0[t] *= al; O1[t] *= al; }
    if (hi == 0) mll[w][j] = l_r * al;
    if (w == 1) {
#pragma unroll
        for (int t = 0; t < 16; t++) {
            obuf[lane][t]      = O0[t];
            obuf[lane][t + 16] = O1[t];
        }
    }
    __syncthreads();
    if (w == 0) {
#pragma unroll
        for (int t = 0; t < 16; t++) {
            O0[t] += obuf[lane][t];
            O1[t] += obuf[lane][t + 16];
        }
        float lt = mll[0][j] + mll[1][j];
        int qrow = qrow0 + j;
        float qm = (qrow < qlen) ? (1.0f / lt) : 0.f;
        float* ob = out + (size_t)(b * 2048 + qrow) * 1024 + h * 64;
#pragma unroll
        for (int s = 0; s < 4; s++) {
            float4 oa, obv;
            oa.x = O0[4*s+0] * qm; oa.y = O0[4*s+1] * qm; oa.z = O0[4*s+2] * qm; oa.w = O0[4*s+3] * qm;
            obv.x = O1[4*s+0] * qm; obv.y = O1[4*s+1] * qm; obv.z = O1[4*s+2] * qm; obv.w = O1[4*s+3] * qm;
            *reinterpret_cast<float4*>(ob + 8 * s + 4 * hi) = oa;
            *reinterpret_cast<float4*>(ob + 32 + 8 * s + 4 * hi) = obv;
        }
    }
}

// ---------------------------------------------------------------------------
extern "C" void kernel_launch(void* const* d_in, const int* in_sizes, int n_in,
                              void* d_out, int out_size, void* d_ws, size_t ws_size,
                              hipStream_t stream)
{
    const float* Q_seq = (const float*)d_in[0];
    const float* K_seq = (const float*)d_in[1];
    const float* V_seq = (const float*)d_in[2];
    const int*   Q_len = (const int*)d_in[3];
    const int*   V_len = (const int*)d_in[4];
    const float* WQ    = (const float*)d_in[5];
    const float* WK    = (const float*)d_in[6];
    const float* WV    = (const float*)d_in[7];
    float* outp = (float*)d_out;

    // ws layout (bf16 elems): wt[3*1M] | qh[4M] | kh[4M] | vh[4M] | abf[3*4M]
    unsigned short* wsb = (unsigned short*)d_ws;
    unsigned short* wt  = wsb;
    unsigned short* qp  = wsb + (size_t)3 * 1048576u;
    unsigned short* kp  = qp + 4194304u;
    unsigned short* vhp = kp + 4194304u;
    unsigned short* abf = vhp + 4194304u;

    size_t need = ((size_t)3 * 1048576u + 3u * 4194304u + (size_t)3 * 4194304u) * 2u;
    bool precvt = ws_size >= need;

    wt_kernel<<<dim3(16, 16, 3), 256, 0, stream>>>(WQ, WK, WV, wt);
    if (precvt) {
        cvt_kernel<<<dim3(4096, 3), 256, 0, stream>>>(Q_seq, K_seq, V_seq, Q_len, V_len, abf);
        proj_kernel<true><<<dim3(8, 32, 3), 256, 0, stream>>>(
            Q_seq, K_seq, V_seq, abf, wt, Q_len, V_len, qp, kp, vhp);
    } else {
        proj_kernel<false><<<dim3(8, 32, 3), 256, 0, stream>>>(
            Q_seq, K_seq, V_seq, nullptr, wt, Q_len, V_len, qp, kp, vhp);
    }
    attn_kernel<<<dim3(2048), 128, 0, stream>>>(qp, kp, vhp, Q_len, V_len, outp);
}

// Round 11
// 68.011 us; speedup vs baseline: 2.1408x; 1.2395x over previous
//
#include <hip/hip_runtime.h>

// MultiHeadAttn: B=2, T=2048, D=1024, H=16, dh=64
// R11: permuted per-head tile layouts -> ALL attn fragment loads coalesced
// (base + c*1024B + lane*16B), plus 2 q-tiles per wave (halves K/V traffic).
// Layout per (b,h), per 64-row tile, element (row, d):
//   off = ((d>>4)*2 + ((d>>3)&1))*512 + row*8 + (d&7)     [K, Q]
// V per tile, element (d, key):
//   off = ((key>>4)*2 + ((key>>3)&1))*512 + d*8 + (key&7)

using short8   = __attribute__((ext_vector_type(8))) short;
using floatx4  = __attribute__((ext_vector_type(4))) float;
using floatx16 = __attribute__((ext_vector_type(16))) float;
using uintx4   = __attribute__((ext_vector_type(4))) unsigned int;
using ushort4v = __attribute__((ext_vector_type(4))) unsigned short;

__device__ __forceinline__ unsigned short f2bf(float f) {
    unsigned int u = __builtin_bit_cast(unsigned int, f);
    u += 0x7fffu + ((u >> 16) & 1u);
    return (unsigned short)(u >> 16);
}

// ---------------------------------------------------------------------------
// Kernel 0: fp32 -> bf16 convert of needed rows.
// ---------------------------------------------------------------------------
__global__ __launch_bounds__(256) void cvt_kernel(
    const float* __restrict__ Qs, const float* __restrict__ Ks,
    const float* __restrict__ Vs, const int* __restrict__ Qlen,
    const int* __restrict__ Vlen, unsigned short* __restrict__ abf)
{
    int z = blockIdx.y, row = blockIdx.x;
    int b = row >> 11, rib = row & 2047;
    int ql = Qlen[b]; int vl = Vlen[b]; int vle = vl ? vl : 2048;
    int lim = (z == 0) ? ((ql + 127) & ~127) : ((vle + 127) & ~127);
    if (rib >= lim) return;
    const float* src = (z == 0) ? Qs : ((z == 1) ? Ks : Vs);
    int t = threadIdx.x;
    float4 v = *reinterpret_cast<const float4*>(src + (size_t)row * 1024 + t * 4);
    ushort4v o;
    o[0] = f2bf(v.x); o[1] = f2bf(v.y); o[2] = f2bf(v.z); o[3] = f2bf(v.w);
    *reinterpret_cast<ushort4v*>(abf + (size_t)z * 4194304u + (size_t)row * 1024 + t * 4) = o;
}

// ---------------------------------------------------------------------------
// Kernel 1: W -> W^T bf16
// ---------------------------------------------------------------------------
__global__ __launch_bounds__(256) void wt_kernel(
    const float* __restrict__ W0, const float* __restrict__ W1,
    const float* __restrict__ W2, unsigned short* __restrict__ out)
{
    __shared__ float tile[64][65];
    int z = blockIdx.z;
    const float* W = (z == 0) ? W0 : ((z == 1) ? W1 : W2);
    unsigned short* O = out + (size_t)z * 1048576u;
    int r0 = blockIdx.y * 64, c0 = blockIdx.x * 64;
    int t = threadIdx.x;
#pragma unroll
    for (int i = 0; i < 16; i++) {
        int idx = t + i * 256; int r = idx >> 6, c = idx & 63;
        tile[r][c] = W[(size_t)(r0 + r) * 1024 + c0 + c];
    }
    __syncthreads();
#pragma unroll
    for (int i = 0; i < 16; i++) {
        int idx = t + i * 256; int c = idx >> 6, r = idx & 63;
        O[(size_t)(c0 + c) * 1024 + r0 + r] = f2bf(tile[r][c]);
    }
}

// ---------------------------------------------------------------------------
// Kernel 2: projection GEMM; epilogue writes PERMUTED per-head tile layouts.
// ---------------------------------------------------------------------------
template <bool PRECVT>
__global__ __launch_bounds__(256) void proj_kernel(
    const float* __restrict__ Qs, const float* __restrict__ Ks,
    const float* __restrict__ Vs, const unsigned short* __restrict__ abf,
    const unsigned short* __restrict__ wt,
    const int* __restrict__ Qlen, const int* __restrict__ Vlen,
    unsigned short* __restrict__ q, unsigned short* __restrict__ k,
    unsigned short* __restrict__ vh)
{
    __shared__ alignas(16) unsigned short As[128][72];
    __shared__ alignas(16) unsigned short Bs[128][72];

    int z = blockIdx.z;
    int tid = threadIdx.x;
    int m0 = blockIdx.y * 128, n0 = blockIdx.x * 128;
    int b = m0 >> 11, rib = m0 & 2047;
    int ql = Qlen[b]; int vl = Vlen[b]; int vle = vl ? vl : 2048;
    int lim = (z == 0) ? ((ql + 127) & ~127) : ((vle + 127) & ~127);
    if (rib >= lim) return;

    const float* Af = (z == 0) ? Qs : ((z == 1) ? Ks : Vs);
    const unsigned short* Ab = abf + (size_t)z * 4194304u;
    const unsigned short* Bt = wt + (size_t)z * 1048576u;

    int w = tid >> 6, lane = tid & 63, g = lane >> 4, lr = lane & 15;
    int wr = w >> 1, wc = w & 1;

    floatx4 acc[4][4];
#pragma unroll
    for (int m = 0; m < 4; m++)
#pragma unroll
        for (int n = 0; n < 4; n++) {
#pragma unroll
            for (int r = 0; r < 4; r++) acc[m][n][r] = 0.f;
        }

    int srow = tid >> 1, scol = (tid & 1) * 32;

    short8 pa[4], pb[4];
    float4 fa[8];

    if constexpr (PRECVT) {
#pragma unroll
        for (int i = 0; i < 4; i++)
            pa[i] = *reinterpret_cast<const short8*>(Ab + (size_t)(m0 + srow) * 1024 + scol + i * 8);
    } else {
#pragma unroll
        for (int i = 0; i < 8; i++)
            fa[i] = *reinterpret_cast<const float4*>(Af + (size_t)(m0 + srow) * 1024 + scol + i * 4);
    }
#pragma unroll
    for (int i = 0; i < 4; i++)
        pb[i] = *reinterpret_cast<const short8*>(Bt + (size_t)(n0 + srow) * 1024 + scol + i * 8);

    for (int kb = 0; kb < 1024; kb += 64) {
        __syncthreads();
        if constexpr (PRECVT) {
#pragma unroll
            for (int i = 0; i < 4; i++)
                *reinterpret_cast<short8*>(&As[srow][scol + i * 8]) = pa[i];
        } else {
#pragma unroll
            for (int i = 0; i < 4; i++) {
                short8 hcv;
                hcv[0] = (short)f2bf(fa[2*i].x);   hcv[1] = (short)f2bf(fa[2*i].y);
                hcv[2] = (short)f2bf(fa[2*i].z);   hcv[3] = (short)f2bf(fa[2*i].w);
                hcv[4] = (short)f2bf(fa[2*i+1].x); hcv[5] = (short)f2bf(fa[2*i+1].y);
                hcv[6] = (short)f2bf(fa[2*i+1].z); hcv[7] = (short)f2bf(fa[2*i+1].w);
                *reinterpret_cast<short8*>(&As[srow][scol + i * 8]) = hcv;
            }
        }
#pragma unroll
        for (int i = 0; i < 4; i++)
            *reinterpret_cast<short8*>(&Bs[srow][scol + i * 8]) = pb[i];
        __syncthreads();

        if (kb + 64 < 1024) {
            if constexpr (PRECVT) {
#pragma unroll
                for (int i = 0; i < 4; i++)
                    pa[i] = *reinterpret_cast<const short8*>(Ab + (size_t)(m0 + srow) * 1024 + kb + 64 + scol + i * 8);
            } else {
#pragma unroll
                for (int i = 0; i < 8; i++)
                    fa[i] = *reinterpret_cast<const float4*>(Af + (size_t)(m0 + srow) * 1024 + kb + 64 + scol + i * 4);
            }
#pragma unroll
            for (int i = 0; i < 4; i++)
                pb[i] = *reinterpret_cast<const short8*>(Bt + (size_t)(n0 + srow) * 1024 + kb + 64 + scol + i * 8);
        }

#pragma unroll
        for (int kc = 0; kc < 2; kc++) {
            short8 af[4], bf[4];
#pragma unroll
            for (int m = 0; m < 4; m++)
                af[m] = *reinterpret_cast<const short8*>(&As[wr * 64 + m * 16 + lr][kc * 32 + g * 8]);
#pragma unroll
            for (int n = 0; n < 4; n++)
                bf[n] = *reinterpret_cast<const short8*>(&Bs[wc * 64 + n * 16 + lr][kc * 32 + g * 8]);
#pragma unroll
            for (int m = 0; m < 4; m++)
#pragma unroll
                for (int n = 0; n < 4; n++)
                    acc[m][n] = __builtin_amdgcn_mfma_f32_16x16x32_bf16(af[m], bf[n], acc[m][n], 0, 0, 0);
        }
    }

    // epilogue -> permuted per-head tile layouts
    if (z < 2) {
        unsigned short* outp = (z == 0) ? q : k;
#pragma unroll
        for (int m = 0; m < 4; m++) {
            int row0 = m0 + wr * 64 + m * 16 + g * 4;
            int tb = row0 & 2047;
            int tile = tb >> 6, rin = tb & 63;        // rin 4-aligned
#pragma unroll
            for (int n = 0; n < 4; n++) {
                int col = n0 + wc * 64 + n * 16 + lr;
                int hh = col >> 6, dd = col & 63;
                int cc = dd >> 4, h2 = (dd >> 3) & 1, u = dd & 7;
                size_t base = ((size_t)(b * 16 + hh) * 32 + tile) * 4096
                            + (size_t)((cc * 2 + h2) * 512) + (size_t)rin * 8 + u;
#pragma unroll
                for (int r = 0; r < 4; r++)
                    outp[base + (size_t)r * 8] = f2bf(acc[m][n][r]);
            }
        }
    } else {
#pragma unroll
        for (int m = 0; m < 4; m++) {
            int row0 = m0 + wr * 64 + m * 16 + g * 4;
            int tg = row0 & 2047;                      // key index, 4-aligned
            int tile = tg >> 6, kin = tg & 63;
            int cc = kin >> 4, h2 = (kin >> 3) & 1, u = kin & 7;   // u in {0,4}
#pragma unroll
            for (int n = 0; n < 4; n++) {
                int col = n0 + wc * 64 + n * 16 + lr;
                int hh = col >> 6, dd = col & 63;
                ushort4v pk;
#pragma unroll
                for (int r = 0; r < 4; r++) pk[r] = f2bf(acc[m][n][r]);
                size_t addr = ((size_t)(b * 16 + hh) * 32 + tile) * 4096
                            + (size_t)((cc * 2 + h2) * 512) + (size_t)dd * 8 + u;
                *reinterpret_cast<ushort4v*>(vh + addr) = pk;
            }
        }
    }
}

// ---------------------------------------------------------------------------
// Kernel 3: flash attention. 128 thr = 2 waves; block = 64 q rows (2 q-tiles
// A,B per wave); split-2 over KV tiles; no-barrier reg-direct loop with
// coalesced fragment loads (base + c*1024B + lane*16B); pinned prefetch;
// 2-qtile combine at end. Grid 1024 (XCD-balanced).
// ---------------------------------------------------------------------------
__global__ __launch_bounds__(128) void attn_kernel(
    const unsigned short* __restrict__ q, const unsigned short* __restrict__ k,
    const unsigned short* __restrict__ vh, const int* __restrict__ Qlen,
    const int* __restrict__ Vlen, float* __restrict__ out)
{
    __shared__ float obuf[2][64][33];
    __shared__ float mlm[2][2][33];
    __shared__ float mll[2][2][33];

    int tid = threadIdx.x;
    int w = tid >> 6, lane = tid & 63;
    int j = lane & 31, hi = lane >> 5;

    int blk = blockIdx.x;
    int x = blk & 7, idx = blk >> 3;
    int bh = x + 8 * (idx >> 5), qb = idx & 31;
    int b = bh >> 4, h = bh & 15;
    int qlen = Qlen[b]; int vl = Vlen[b]; int vle = vl ? vl : 2048;

    if (qb * 64 >= qlen) {   // dead block -> zeros
        int zr = qb * 64 + (tid >> 1);
        float* p = out + (size_t)(b * 2048 + zr) * 1024 + h * 64 + (tid & 1) * 32;
        float4 z4; z4.x = 0.f; z4.y = 0.f; z4.z = 0.f; z4.w = 0.f;
#pragma unroll
        for (int s = 0; s < 8; s++) *reinterpret_cast<float4*>(p + 4 * s) = z4;
        return;
    }

    int nt = (vle + 63) >> 6;
    int ntw = (nt - w + 1) >> 1;

    size_t hb = (size_t)(b * 16 + h) * 131072u;
    const unsigned short* kh = k + hb;
    const unsigned short* vb = vh + hb;
    int lo = hi * 512 + j * 8;        // lane fragment offset (elems)

    // Q fragments (coalesced)
    short8 qfA[4], qfB[4];
    {
        const unsigned short* qt = q + hb + (size_t)qb * 4096 + lo;
#pragma unroll
        for (int c = 0; c < 4; c++) {
            qfA[c] = *reinterpret_cast<const short8*>(qt + c * 1024);
            qfB[c] = *reinterpret_cast<const short8*>(qt + c * 1024 + 256);
        }
    }

    // initial prefetch (tile w, clamped)
    short8 kf0[4], kf1[4], vf0[4], vf1[4];
    {
        int t0 = (w < nt) ? w : (nt - 1);
        const unsigned short* kt0 = kh + (size_t)t0 * 4096 + lo;
        const unsigned short* vt0 = vb + (size_t)t0 * 4096 + lo;
#pragma unroll
        for (int c = 0; c < 4; c++) {
            kf0[c] = *reinterpret_cast<const short8*>(kt0 + c * 1024);
            kf1[c] = *reinterpret_cast<const short8*>(kt0 + c * 1024 + 256);
            vf0[c] = *reinterpret_cast<const short8*>(vt0 + c * 1024);
            vf1[c] = *reinterpret_cast<const short8*>(vt0 + c * 1024 + 256);
        }
    }
    __builtin_amdgcn_sched_barrier(0);

    floatx16 OA0, OA1, OB0, OB1;
#pragma unroll
    for (int t = 0; t < 16; t++) { OA0[t] = 0.f; OA1[t] = 0.f; OB0[t] = 0.f; OB1[t] = 0.f; }
    float mA = -3.0e38f, lA = 0.f, mB = -3.0e38f, lB = 0.f;

    const float CEXP = 0.18033688011112042f;

    for (int mi = 0; mi < ntw; ++mi) {
        int tix = w + 2 * mi;
        int kt = tix << 6;
        int tnx = tix + 2; if (tnx >= nt) tnx = nt - 1;

        // ================= Q-TILE A =================
        floatx16 s0, s1;
#pragma unroll
        for (int t = 0; t < 16; t++) { s0[t] = 0.f; s1[t] = 0.f; }
#pragma unroll
        for (int c = 0; c < 4; c++) {
            s0 = __builtin_amdgcn_mfma_f32_32x32x16_bf16(kf0[c], qfA[c], s0, 0, 0, 0);
            s1 = __builtin_amdgcn_mfma_f32_32x32x16_bf16(kf1[c], qfA[c], s1, 0, 0, 0);
        }
        if (kt + 64 > vle) {
#pragma unroll
            for (int t = 0; t < 16; t++) {
                int kl = (t & 3) + 8 * (t >> 2) + 4 * hi;
                if (kt + kl >= vle)      s0[t] = -8.0e12f;
                if (kt + 32 + kl >= vle) s1[t] = -8.0e12f;
            }
        }
        {   // softmax A
            float mx = s0[0];
#pragma unroll
            for (int t = 1; t < 16; t++) mx = fmaxf(mx, s0[t]);
#pragma unroll
            for (int t = 0; t < 16; t++) mx = fmaxf(mx, s1[t]);
            float lm = fmaxf(mx, __shfl_xor(mx, 32));
            if (__any(lm > mA + 64.f)) {
                float mn = fmaxf(mA, lm);
                float al = __builtin_amdgcn_exp2f((mA - mn) * CEXP);
                mA = mn; lA *= al;
#pragma unroll
                for (int t = 0; t < 16; t++) { OA0[t] *= al; OA1[t] *= al; }
            }
            float nm = -mA * CEXP;
#pragma unroll
            for (int t = 0; t < 16; t++) {
                s0[t] = __builtin_amdgcn_exp2f(fmaf(s0[t], CEXP, nm));
                s1[t] = __builtin_amdgcn_exp2f(fmaf(s1[t], CEXP, nm));
            }
            float rs = 0.f;
#pragma unroll
            for (int t = 0; t < 16; t++) rs += s0[t] + s1[t];
            lA += rs;
        }
        {   // pack A + PV A
            unsigned int pbw[4][4];
            unsigned int D[4][2];
#pragma unroll
            for (int s = 0; s < 4; s++) {
                asm("v_cvt_pk_bf16_f32 %0, %1, %2" : "=v"(D[s][0]) : "v"(s0[4*s+0]), "v"(s0[4*s+1]));
                asm("v_cvt_pk_bf16_f32 %0, %1, %2" : "=v"(D[s][1]) : "v"(s0[4*s+2]), "v"(s0[4*s+3]));
            }
#pragma unroll
            for (int u = 0; u < 2; u++) {
                asm volatile("v_permlane32_swap_b32 %0, %1" : "+v"(D[0][u]), "+v"(D[1][u]));
                asm volatile("v_permlane32_swap_b32 %0, %1" : "+v"(D[2][u]), "+v"(D[3][u]));
                pbw[0][u] = D[0][u]; pbw[0][u + 2] = D[1][u];
                pbw[1][u] = D[2][u]; pbw[1][u + 2] = D[3][u];
            }
#pragma unroll
            for (int s = 0; s < 4; s++) {
                asm("v_cvt_pk_bf16_f32 %0, %1, %2" : "=v"(D[s][0]) : "v"(s1[4*s+0]), "v"(s1[4*s+1]));
                asm("v_cvt_pk_bf16_f32 %0, %1, %2" : "=v"(D[s][1]) : "v"(s1[4*s+2]), "v"(s1[4*s+3]));
            }
#pragma unroll
            for (int u = 0; u < 2; u++) {
                asm volatile("v_permlane32_swap_b32 %0, %1" : "+v"(D[0][u]), "+v"(D[1][u]));
                asm volatile("v_permlane32_swap_b32 %0, %1" : "+v"(D[2][u]), "+v"(D[3][u]));
                pbw[2][u] = D[0][u]; pbw[2][u + 2] = D[1][u];
                pbw[3][u] = D[2][u]; pbw[3][u + 2] = D[3][u];
            }
#pragma unroll
            for (int c = 0; c < 4; c++) {
                uintx4 pw; pw[0] = pbw[c][0]; pw[1] = pbw[c][1]; pw[2] = pbw[c][2]; pw[3] = pbw[c][3];
                short8 pf = __builtin_bit_cast(short8, pw);
                OA0 = __builtin_amdgcn_mfma_f32_32x32x16_bf16(vf0[c], pf, OA0, 0, 0, 0);
                OA1 = __builtin_amdgcn_mfma_f32_32x32x16_bf16(vf1[c], pf, OA1, 0, 0, 0);
            }
        }

        // ================= Q-TILE B =================
#pragma unroll
        for (int t = 0; t < 16; t++) { s0[t] = 0.f; s1[t] = 0.f; }
#pragma unroll
        for (int c = 0; c < 4; c++) {
            s0 = __builtin_amdgcn_mfma_f32_32x32x16_bf16(kf0[c], qfB[c], s0, 0, 0, 0);
            s1 = __builtin_amdgcn_mfma_f32_32x32x16_bf16(kf1[c], qfB[c], s1, 0, 0, 0);
        }
        // kf dead: prefetch next K (pinned)
        {
            const unsigned short* kn = kh + (size_t)tnx * 4096 + lo;
#pragma unroll
            for (int c = 0; c < 4; c++) {
                kf0[c] = *reinterpret_cast<const short8*>(kn + c * 1024);
                kf1[c] = *reinterpret_cast<const short8*>(kn + c * 1024 + 256);
            }
        }
        __builtin_amdgcn_sched_barrier(0);

        if (kt + 64 > vle) {
#pragma unroll
            for (int t = 0; t < 16; t++) {
                int kl = (t & 3) + 8 * (t >> 2) + 4 * hi;
                if (kt + kl >= vle)      s0[t] = -8.0e12f;
                if (kt + 32 + kl >= vle) s1[t] = -8.0e12f;
            }
        }
        {   // softmax B
            float mx = s0[0];
#pragma unroll
            for (int t = 1; t < 16; t++) mx = fmaxf(mx, s0[t]);
#pragma unroll
            for (int t = 0; t < 16; t++) mx = fmaxf(mx, s1[t]);
            float lm = fmaxf(mx, __shfl_xor(mx, 32));
            if (__any(lm > mB + 64.f)) {
                float mn = fmaxf(mB, lm);
                float al = __builtin_amdgcn_exp2f((mB - mn) * CEXP);
                mB = mn; lB *= al;
#pragma unroll
                for (int t = 0; t < 16; t++) { OB0[t] *= al; OB1[t] *= al; }
            }
            float nm = -mB * CEXP;
#pragma unroll
            for (int t = 0; t < 16; t++) {
                s0[t] = __builtin_amdgcn_exp2f(fmaf(s0[t], CEXP, nm));
                s1[t] = __builtin_amdgcn_exp2f(fmaf(s1[t], CEXP, nm));
            }
            float rs = 0.f;
#pragma unroll
            for (int t = 0; t < 16; t++) rs += s0[t] + s1[t];
            lB += rs;
        }
        {   // pack B + PV B
            unsigned int pbw[4][4];
            unsigned int D[4][2];
#pragma unroll
            for (int s = 0; s < 4; s++) {
                asm("v_cvt_pk_bf16_f32 %0, %1, %2" : "=v"(D[s][0]) : "v"(s0[4*s+0]), "v"(s0[4*s+1]));
                asm("v_cvt_pk_bf16_f32 %0, %1, %2" : "=v"(D[s][1]) : "v"(s0[4*s+2]), "v"(s0[4*s+3]));
            }
#pragma unroll
            for (int u = 0; u < 2; u++) {
                asm volatile("v_permlane32_swap_b32 %0, %1" : "+v"(D[0][u]), "+v"(D[1][u]));
                asm volatile("v_permlane32_swap_b32 %0, %1" : "+v"(D[2][u]), "+v"(D[3][u]));
                pbw[0][u] = D[0][u]; pbw[0][u + 2] = D[1][u];
                pbw[1][u] = D[2][u]; pbw[1][u + 2] = D[3][u];
            }
#pragma unroll
            for (int s = 0; s < 4; s++) {
                asm("v_cvt_pk_bf16_f32 %0, %1, %2" : "=v"(D[s][0]) : "v"(s1[4*s+0]), "v"(s1[4*s+1]));
                asm("v_cvt_pk_bf16_f32 %0, %1, %2" : "=v"(D[s][1]) : "v"(s1[4*s+2]), "v"(s1[4*s+3]));
            }
#pragma unroll
            for (int u = 0; u < 2; u++) {
                asm volatile("v_permlane32_swap_b32 %0, %1" : "+v"(D[0][u]), "+v"(D[1][u]));
                asm volatile("v_permlane32_swap_b32 %0, %1" : "+v"(D[2][u]), "+v"(D[3][u]));
                pbw[2][u] = D[0][u]; pbw[2][u + 2] = D[1][u];
                pbw[3][u] = D[2][u]; pbw[3][u + 2] = D[3][u];
            }
#pragma unroll
            for (int c = 0; c < 4; c++) {
                uintx4 pw; pw[0] = pbw[c][0]; pw[1] = pbw[c][1]; pw[2] = pbw[c][2]; pw[3] = pbw[c][3];
                short8 pf = __builtin_bit_cast(short8, pw);
                OB0 = __builtin_amdgcn_mfma_f32_32x32x16_bf16(vf0[c], pf, OB0, 0, 0, 0);
                OB1 = __builtin_amdgcn_mfma_f32_32x32x16_bf16(vf1[c], pf, OB1, 0, 0, 0);
            }
        }
        // vf dead: prefetch next V (pinned)
        {
            const unsigned short* vn = vb + (size_t)tnx * 4096 + lo;
#pragma unroll
            for (int c = 0; c < 4; c++) {
                vf0[c] = *reinterpret_cast<const short8*>(vn + c * 1024);
                vf1[c] = *reinterpret_cast<const short8*>(vn + c * 1024 + 256);
            }
        }
        __builtin_amdgcn_sched_barrier(0);
    }

    // ================= combine (2 waves x 2 qtiles) ========================
    lA = lA + __shfl_xor(lA, 32);
    lB = lB + __shfl_xor(lB, 32);
    if (hi == 0) { mlm[0][w][j] = mA; mlm[1][w][j] = mB; }
    __syncthreads();
    float MA = fmaxf(mlm[0][0][j], mlm[0][1][j]);
    float MB = fmaxf(mlm[1][0][j], mlm[1][1][j]);
    float alA = __builtin_amdgcn_exp2f((mA - MA) * CEXP);
    float alB = __builtin_amdgcn_exp2f((mB - MB) * CEXP);
#pragma unroll
    for (int t = 0; t < 16; t++) { OA0[t] *= alA; OA1[t] *= alA; OB0[t] *= alB; OB1[t] *= alB; }
    if (hi == 0) { mll[0][w][j] = lA * alA; mll[1][w][j] = lB * alB; }
    if (w == 1) {
#pragma unroll
        for (int t = 0; t < 16; t++) {
            obuf[0][lane][t]      = OA0[t];
            obuf[0][lane][t + 16] = OA1[t];
            obuf[1][lane][t]      = OB0[t];
            obuf[1][lane][t + 16] = OB1[t];
        }
    }
    __syncthreads();
    if (w == 0) {
#pragma unroll
        for (int t = 0; t < 16; t++) {
            OA0[t] += obuf[0][lane][t];
            OA1[t] += obuf[0][lane][t + 16];
            OB0[t] += obuf[1][lane][t];
            OB1[t] += obuf[1][lane][t + 16];
        }
        float ltA = mll[0][0][j] + mll[0][1][j];
        float ltB = mll[1][0][j] + mll[1][1][j];
        int qrA = qb * 64 + j, qrB = qb * 64 + 32 + j;
        float qmA = (qrA < qlen) ? (1.0f / ltA) : 0.f;
        float qmB = (qrB < qlen) ? (1.0f / ltB) : 0.f;
        float* oa = out + (size_t)(b * 2048 + qrA) * 1024 + h * 64;
        float* ob = out + (size_t)(b * 2048 + qrB) * 1024 + h * 64;
#pragma unroll
        for (int s = 0; s < 4; s++) {
            float4 v0, v1;
            v0.x = OA0[4*s+0] * qmA; v0.y = OA0[4*s+1] * qmA; v0.z = OA0[4*s+2] * qmA; v0.w = OA0[4*s+3] * qmA;
            v1.x = OA1[4*s+0] * qmA; v1.y = OA1[4*s+1] * qmA; v1.z = OA1[4*s+2] * qmA; v1.w = OA1[4*s+3] * qmA;
            *reinterpret_cast<float4*>(oa + 8 * s + 4 * hi) = v0;
            *reinterpret_cast<float4*>(oa + 32 + 8 * s + 4 * hi) = v1;
            v0.x = OB0[4*s+0] * qmB; v0.y = OB0[4*s+1] * qmB; v0.z = OB0[4*s+2] * qmB; v0.w = OB0[4*s+3] * qmB;
            v1.x = OB1[4*s+0] * qmB; v1.y = OB1[4*s+1] * qmB; v1.z = OB1[4*s+2] * qmB; v1.w = OB1[4*s+3] * qmB;
            *reinterpret_cast<float4*>(ob + 8 * s + 4 * hi) = v0;
            *reinterpret_cast<float4*>(ob + 32 + 8 * s + 4 * hi) = v1;
        }
    }
}

// ---------------------------------------------------------------------------
extern "C" void kernel_launch(void* const* d_in, const int* in_sizes, int n_in,
                              void* d_out, int out_size, void* d_ws, size_t ws_size,
                              hipStream_t stream)
{
    const float* Q_seq = (const float*)d_in[0];
    const float* K_seq = (const float*)d_in[1];
    const float* V_seq = (const float*)d_in[2];
    const int*   Q_len = (const int*)d_in[3];
    const int*   V_len = (const int*)d_in[4];
    const float* WQ    = (const float*)d_in[5];
    const float* WK    = (const float*)d_in[6];
    const float* WV    = (const float*)d_in[7];
    float* outp = (float*)d_out;

    unsigned short* wsb = (unsigned short*)d_ws;
    unsigned short* wt  = wsb;
    unsigned short* qp  = wsb + (size_t)3 * 1048576u;
    unsigned short* kp  = qp + 4194304u;
    unsigned short* vhp = kp + 4194304u;
    unsigned short* abf = vhp + 4194304u;

    size_t need = ((size_t)3 * 1048576u + 3u * 4194304u + (size_t)3 * 4194304u) * 2u;
    bool precvt = ws_size >= need;

    wt_kernel<<<dim3(16, 16, 3), 256, 0, stream>>>(WQ, WK, WV, wt);
    if (precvt) {
        cvt_kernel<<<dim3(4096, 3), 256, 0, stream>>>(Q_seq, K_seq, V_seq, Q_len, V_len, abf);
        proj_kernel<true><<<dim3(8, 32, 3), 256, 0, stream>>>(
            Q_seq, K_seq, V_seq, abf, wt, Q_len, V_len, qp, kp, vhp);
    } else {
        proj_kernel<false><<<dim3(8, 32, 3), 256, 0, stream>>>(
            Q_seq, K_seq, V_seq, nullptr, wt, Q_len, V_len, qp, kp, vhp);
    }
    attn_kernel<<<dim3(1024), 128, 0, stream>>>(qp, kp, vhp, Q_len, V_len, outp);
}